// Round 1
// baseline (1117.784 us; speedup 1.0000x reference)
//
#include <hip/hip_runtime.h>
#include <hip/hip_bf16.h>

// GAE forward. Pipeline:
//   detect(edge dtype) -> init -> count(deg) -> scan(rowptr,dinv) -> scatter(CSR)
//   -> gemm(x,W1,relu) -> gemm(,W2) -> 3x[gemm(convW); mp(gather+bias+relu)]
//   -> pool(mean,max) -> head(tiny MLPs -> ge[128], s=sigmoid(|v|^2)) -> fill(s)
// edge_probs is constant: node_emb rows are all the same broadcast vector v,
// so logit = sum(v*v) for every edge.

// -------------------- CSR build --------------------

__global__ void detect_i64_kernel(const int* __restrict__ ei, int* __restrict__ flag) {
  if (threadIdx.x == 0 && blockIdx.x == 0) {
    int all0 = 1;
    for (int i = 0; i < 128; ++i) {
      if (ei[2 * i + 1] != 0) { all0 = 0; break; }
    }
    flag[0] = all0;  // 1 => values are int64 (high words all zero)
  }
}

__global__ void init_kernel(int* __restrict__ cnt, int* __restrict__ fill,
                            float* __restrict__ pooled, int N) {
  int i = blockIdx.x * 256 + threadIdx.x;
  if (i < N) { cnt[i] = 0; fill[i] = 0; }
  if (i < 512) pooled[i] = 0.f;  // sum[0:256]=0, max[256:512]=+0.0 bits (h>=0)
}

__global__ void count_kernel(const int* __restrict__ ei, const int* __restrict__ flag,
                             int* __restrict__ cnt, int E) {
  int e = blockIdx.x * 256 + threadIdx.x;
  if (e >= E) return;
  int d;
  if (flag[0]) d = (int)((const long long*)ei)[(size_t)E + e];
  else         d = ei[(size_t)E + e];
  atomicAdd(&cnt[d], 1);
}

__global__ __launch_bounds__(1024) void scan_kernel(const int* __restrict__ cnt,
                                                    int* __restrict__ rowptr,
                                                    float* __restrict__ dinv, int N) {
  __shared__ int sums[1024];
  int t = threadIdx.x;
  int CH = (N + 1023) / 1024;
  int beg = t * CH;
  int end = min(beg + CH, N);
  int s = 0;
  for (int i = beg; i < end; ++i) s += cnt[i];
  sums[t] = s;
  __syncthreads();
  for (int off = 1; off < 1024; off <<= 1) {
    int v = sums[t];
    int add = (t >= off) ? sums[t - off] : 0;
    __syncthreads();
    sums[t] = v + add;
    __syncthreads();
  }
  int prefix = (t > 0) ? sums[t - 1] : 0;
  for (int i = beg; i < end; ++i) {
    int c = cnt[i];
    rowptr[i] = prefix;
    prefix += c;
    dinv[i] = rsqrtf((float)(c + 1));  // +1 self-loop; deg always > 0
  }
  if (t == 1023) rowptr[N] = sums[1023];
}

__global__ void scatter_kernel(const int* __restrict__ ei, const int* __restrict__ flag,
                               const int* __restrict__ rowptr, int* __restrict__ fill,
                               int* __restrict__ col, int E) {
  int e = blockIdx.x * 256 + threadIdx.x;
  if (e >= E) return;
  int s, d;
  if (flag[0]) {
    const long long* e64 = (const long long*)ei;
    s = (int)e64[e];
    d = (int)e64[(size_t)E + e];
  } else {
    s = ei[e];
    d = ei[(size_t)E + e];
  }
  int pos = rowptr[d] + atomicAdd(&fill[d], 1);
  col[pos] = s;
}

// -------------------- GEMM: C[M,256] = act(A[M,K] @ W[K,256] + b) --------------------
// 64x256 tile per 256-thread block; each thread: 16 rows x 4 cols f32 acc.

__global__ __launch_bounds__(256) void gemm_kernel(const float* __restrict__ A,
                                                   const float* __restrict__ W,
                                                   const float* __restrict__ bias,
                                                   float* __restrict__ C,
                                                   int M, int K, int relu) {
  __shared__ float a_s[64][16];   // 4 KB
  __shared__ float w_s[16][256];  // 16 KB
  int t = threadIdx.x;
  int row0 = blockIdx.x * 64;
  int rg = t >> 6;          // wave id 0..3 -> row group
  int c4 = (t & 63) * 4;    // lane -> 4 cols

  float acc[16][4];
#pragma unroll
  for (int i = 0; i < 16; ++i)
#pragma unroll
    for (int j = 0; j < 4; ++j) acc[i][j] = 0.f;

  for (int k0 = 0; k0 < K; k0 += 16) {
    {  // A tile: thread t -> row t/4, kquad t%4
      int r = t >> 2;
      int kk = (t & 3) << 2;
      float4 v = make_float4(0.f, 0.f, 0.f, 0.f);
      int grow = row0 + r;
      if (grow < M) v = *reinterpret_cast<const float4*>(&A[(size_t)grow * K + k0 + kk]);
      a_s[r][kk] = v.x; a_s[r][kk + 1] = v.y; a_s[r][kk + 2] = v.z; a_s[r][kk + 3] = v.w;
    }
#pragma unroll
    for (int q = 0; q < 4; ++q) {  // W tile: 16x256 in 4 passes
      int f = q * 1024 + t * 4;
      int kk = f >> 8;
      int c = f & 255;
      *reinterpret_cast<float4*>(&w_s[kk][c]) =
          *reinterpret_cast<const float4*>(&W[(size_t)(k0 + kk) * 256 + c]);
    }
    __syncthreads();
#pragma unroll
    for (int kq = 0; kq < 4; ++kq) {
      float4 av[16];
#pragma unroll
      for (int i = 0; i < 16; ++i)
        av[i] = *reinterpret_cast<const float4*>(&a_s[rg * 16 + i][kq * 4]);  // wave-uniform: broadcast
#pragma unroll
      for (int kk = 0; kk < 4; ++kk) {
        float4 wv = *reinterpret_cast<const float4*>(&w_s[kq * 4 + kk][c4]);
#pragma unroll
        for (int i = 0; i < 16; ++i) {
          float a = kk == 0 ? av[i].x : kk == 1 ? av[i].y : kk == 2 ? av[i].z : av[i].w;
          acc[i][0] = fmaf(a, wv.x, acc[i][0]);
          acc[i][1] = fmaf(a, wv.y, acc[i][1]);
          acc[i][2] = fmaf(a, wv.z, acc[i][2]);
          acc[i][3] = fmaf(a, wv.w, acc[i][3]);
        }
      }
    }
    __syncthreads();
  }

  float4 bv = make_float4(0.f, 0.f, 0.f, 0.f);
  if (bias) bv = *reinterpret_cast<const float4*>(&bias[c4]);
#pragma unroll
  for (int i = 0; i < 16; ++i) {
    int row = row0 + rg * 16 + i;
    if (row < M) {
      float4 o;
      o.x = acc[i][0] + bv.x; o.y = acc[i][1] + bv.y;
      o.z = acc[i][2] + bv.z; o.w = acc[i][3] + bv.w;
      if (relu) {
        o.x = fmaxf(o.x, 0.f); o.y = fmaxf(o.y, 0.f);
        o.z = fmaxf(o.z, 0.f); o.w = fmaxf(o.w, 0.f);
      }
      *reinterpret_cast<float4*>(&C[(size_t)row * 256 + c4]) = o;
    }
  }
}

// -------------------- message passing: h[n] = relu(sum_{s in in(n)} dinv[s]*dinv[n]*hw[s] + dinv[n]^2*hw[n] + b) ----

__global__ __launch_bounds__(64) void mp_kernel(const float* __restrict__ hw,
                                                const int* __restrict__ rowptr,
                                                const int* __restrict__ col,
                                                const float* __restrict__ dinv,
                                                const float* __restrict__ bias,
                                                float* __restrict__ hout) {
  int n = blockIdx.x;
  int t = threadIdx.x;  // 64 lanes x float4 = 256 cols
  const float4* hw4 = reinterpret_cast<const float4*>(hw);
  float di = dinv[n];
  float4 a = hw4[(size_t)n * 64 + t];
  float w0 = di * di;  // self loop
  float4 acc = make_float4(a.x * w0, a.y * w0, a.z * w0, a.w * w0);
  int beg = rowptr[n], end = rowptr[n + 1];
  for (int j = beg; j < end; ++j) {
    int s = col[j];
    float w = dinv[s] * di;
    float4 hv = hw4[(size_t)s * 64 + t];
    acc.x = fmaf(w, hv.x, acc.x);
    acc.y = fmaf(w, hv.y, acc.y);
    acc.z = fmaf(w, hv.z, acc.z);
    acc.w = fmaf(w, hv.w, acc.w);
  }
  float4 bv = reinterpret_cast<const float4*>(bias)[t];
  acc.x = fmaxf(acc.x + bv.x, 0.f);
  acc.y = fmaxf(acc.y + bv.y, 0.f);
  acc.z = fmaxf(acc.z + bv.z, 0.f);
  acc.w = fmaxf(acc.w + bv.w, 0.f);
  reinterpret_cast<float4*>(hout)[(size_t)n * 64 + t] = acc;
}

// -------------------- pooling: column-wise mean-sum + max over N rows --------------------

__global__ __launch_bounds__(256) void pool_kernel(const float* __restrict__ h,
                                                   float* __restrict__ pooled_sum,
                                                   unsigned* __restrict__ pooled_max, int N) {
  int t = threadIdx.x;  // col
  int r0 = blockIdx.x * 250;
  int r1 = min(r0 + 250, N);
  float s = 0.f, m = 0.f;  // h >= 0 after relu
  for (int r = r0; r < r1; ++r) {
    float v = h[(size_t)r * 256 + t];
    s += v;
    m = fmaxf(m, v);
  }
  atomicAdd(&pooled_sum[t], s);
  atomicMax(&pooled_max[t], __float_as_uint(m));  // valid: non-negative floats
}

// -------------------- head: graph projection + decoder + scalar logit --------------------

__global__ __launch_bounds__(256) void head_kernel(const float* __restrict__ pooled,
                                                   const float* __restrict__ Wg1, const float* __restrict__ bg1,
                                                   const float* __restrict__ Wg2, const float* __restrict__ bg2,
                                                   const float* __restrict__ Wd1, const float* __restrict__ bd1,
                                                   const float* __restrict__ Wd2, const float* __restrict__ bd2,
                                                   float* __restrict__ out_ge, float* __restrict__ s_out, int N) {
  __shared__ float gr[512];
  __shared__ float t1[256];
  __shared__ float ge[128];
  __shared__ float t2[256];
  __shared__ float v[256];
  __shared__ float red[4];
  int t = threadIdx.x;
  gr[t] = pooled[t] / (float)N;                                    // mean
  gr[256 + t] = __uint_as_float(((const unsigned*)pooled)[256 + t]);  // max (bit-stored)
  __syncthreads();
  float acc = bg1[t];
  for (int k = 0; k < 512; ++k) acc = fmaf(gr[k], Wg1[k * 256 + t], acc);
  t1[t] = fmaxf(acc, 0.f);
  __syncthreads();
  if (t < 128) {
    float a = bg2[t];
    for (int k = 0; k < 256; ++k) a = fmaf(t1[k], Wg2[k * 128 + t], a);
    ge[t] = a;
    out_ge[t] = a;  // output 0: graph_embedding
  }
  __syncthreads();
  acc = bd1[t];
  for (int k = 0; k < 128; ++k) acc = fmaf(ge[k], Wd1[k * 256 + t], acc);
  t2[t] = fmaxf(acc, 0.f);
  __syncthreads();
  acc = bd2[t];
  for (int k = 0; k < 256; ++k) acc = fmaf(t2[k], Wd2[k * 256 + t], acc);
  v[t] = acc;
  __syncthreads();
  float p = v[t] * v[t];
  for (int off = 32; off > 0; off >>= 1) p += __shfl_down(p, off, 64);
  if ((t & 63) == 0) red[t >> 6] = p;
  __syncthreads();
  if (t == 0) {
    float ssq = red[0] + red[1] + red[2] + red[3];
    s_out[0] = 1.f / (1.f + expf(-ssq));
  }
}

__global__ void fill_kernel(float* __restrict__ out, const float* __restrict__ s_out, int E) {
  int i = blockIdx.x * 256 + threadIdx.x;
  if (i < E) out[i] = s_out[0];
}

// -------------------- launch --------------------

extern "C" void kernel_launch(void* const* d_in, const int* in_sizes, int n_in,
                              void* d_out, int out_size, void* d_ws, size_t ws_size,
                              hipStream_t stream) {
  const float* x   = (const float*)d_in[0];
  const int*   ei  = (const int*)d_in[1];
  const float* W1  = (const float*)d_in[2];
  const float* b1  = (const float*)d_in[3];
  const float* W2  = (const float*)d_in[4];
  const float* b2  = (const float*)d_in[5];
  const float* cW  = (const float*)d_in[6];
  const float* cb  = (const float*)d_in[7];
  const float* Wg1 = (const float*)d_in[8];
  const float* bg1 = (const float*)d_in[9];
  const float* Wg2 = (const float*)d_in[10];
  const float* bg2 = (const float*)d_in[11];
  const float* Wd1 = (const float*)d_in[12];
  const float* bd1 = (const float*)d_in[13];
  const float* Wd2 = (const float*)d_in[14];
  const float* bd2 = (const float*)d_in[15];
  float* out = (float*)d_out;

  int N = in_sizes[0] / 64;  // 50000
  int E = in_sizes[1] / 2;   // 800000

  size_t off = 0;
  auto walloc = [&](size_t bytes) -> void* {
    void* p = (char*)d_ws + off;
    off += (bytes + 511) & ~(size_t)511;
    return p;
  };
  float* bufA   = (float*)walloc((size_t)N * 256 * 4);
  float* bufB   = (float*)walloc((size_t)N * 256 * 4);
  int*   cnt    = (int*)walloc((size_t)N * 4);
  int*   fillc  = (int*)walloc((size_t)N * 4);
  int*   rowptr = (int*)walloc(((size_t)N + 1) * 4);
  float* dinv   = (float*)walloc((size_t)N * 4);
  int*   col    = (int*)walloc((size_t)E * 4);
  float* pooled = (float*)walloc(512 * 4);
  float* s_out  = (float*)walloc(512);
  int*   flag   = (int*)walloc(512);

  // graph structure (CSR by dst)
  detect_i64_kernel<<<1, 64, 0, stream>>>(ei, flag);
  init_kernel<<<(N + 255) / 256, 256, 0, stream>>>(cnt, fillc, pooled, N);
  count_kernel<<<(E + 255) / 256, 256, 0, stream>>>(ei, flag, cnt, E);
  scan_kernel<<<1, 1024, 0, stream>>>(cnt, rowptr, dinv, N);
  scatter_kernel<<<(E + 255) / 256, 256, 0, stream>>>(ei, flag, rowptr, fillc, col, E);

  int gblocks = (N + 63) / 64;
  // encoder
  gemm_kernel<<<gblocks, 256, 0, stream>>>(x, W1, b1, bufB, N, 64, 1);
  gemm_kernel<<<gblocks, 256, 0, stream>>>(bufB, W2, b2, bufA, N, 256, 0);
  // GCN layers
  for (int l = 0; l < 3; ++l) {
    gemm_kernel<<<gblocks, 256, 0, stream>>>(bufA, cW + (size_t)l * 256 * 256, nullptr, bufB, N, 256, 0);
    mp_kernel<<<N, 64, 0, stream>>>(bufB, rowptr, col, dinv, cb + (size_t)l * 256, bufA);
  }
  // readout
  pool_kernel<<<(N + 249) / 250, 256, 0, stream>>>(bufA, pooled, (unsigned*)(pooled + 256), N);
  head_kernel<<<1, 256, 0, stream>>>(pooled, Wg1, bg1, Wg2, bg2, Wd1, bd1, Wd2, bd2, out, s_out, N);
  fill_kernel<<<(E + 255) / 256, 256, 0, stream>>>(out + 128, s_out, E);
}

// Round 2
// 620.801 us; speedup vs baseline: 1.8006x; 1.8006x over previous
//
#include <hip/hip_runtime.h>
#include <hip/hip_bf16.h>

// GAE forward, bf16 compute path.
//   CSR build (count/scan/scatter) -> cvt x->bf16, pack weights to MFMA frag order
//   -> 5x bf16-MFMA GEMM (encoder x2, conv x3; conv epilogue scales row by dinv)
//   -> 3x mp gather (bf16 rows, f32 accum) -> pool -> head (f32) -> fill(sigmoid const)
// edge_probs is constant: node_emb rows are the same broadcast vector v,
// so logit = sum(v*v) for every edge.

typedef __attribute__((ext_vector_type(8))) short bf16x8;
typedef __attribute__((ext_vector_type(4))) float f32x4;

__device__ __forceinline__ ushort f2bf(float f) {
  union { float f; unsigned u; } v; v.f = f;
  unsigned r = v.u + 0x7FFF + ((v.u >> 16) & 1);  // RNE
  return (ushort)(r >> 16);
}
__device__ __forceinline__ float bf2f(ushort b) {
  union { unsigned u; float f; } v; v.u = ((unsigned)b) << 16;
  return v.f;
}

// -------------------- CSR build --------------------

__global__ void detect_i64_kernel(const int* __restrict__ ei, int* __restrict__ flag) {
  if (threadIdx.x == 0 && blockIdx.x == 0) {
    int all0 = 1;
    for (int i = 0; i < 128; ++i) {
      if (ei[2 * i + 1] != 0) { all0 = 0; break; }
    }
    flag[0] = all0;  // 1 => int64 payload (high words all zero)
  }
}

__global__ void init_kernel(int* __restrict__ cnt, int* __restrict__ fill,
                            float* __restrict__ pooled, int N) {
  int i = blockIdx.x * 256 + threadIdx.x;
  if (i < N) { cnt[i] = 0; fill[i] = 0; }
  if (i < 512) pooled[i] = 0.f;  // sum[0:256]=0, max bits[256:512]=+0.0 (h>=0)
}

__global__ void count_kernel(const int* __restrict__ ei, const int* __restrict__ flag,
                             int* __restrict__ cnt, int E) {
  int e = blockIdx.x * 256 + threadIdx.x;
  if (e >= E) return;
  int d;
  if (flag[0]) d = (int)((const long long*)ei)[(size_t)E + e];
  else         d = ei[(size_t)E + e];
  atomicAdd(&cnt[d], 1);
}

__global__ __launch_bounds__(1024) void scan_kernel(const int* __restrict__ cnt,
                                                    int* __restrict__ rowptr,
                                                    float* __restrict__ dinv, int N) {
  __shared__ int sums[1024];
  int t = threadIdx.x;
  int CH = (N + 1023) / 1024;
  int beg = t * CH;
  int end = min(beg + CH, N);
  int s = 0;
  for (int i = beg; i < end; ++i) s += cnt[i];
  sums[t] = s;
  __syncthreads();
  for (int off = 1; off < 1024; off <<= 1) {
    int v = sums[t];
    int add = (t >= off) ? sums[t - off] : 0;
    __syncthreads();
    sums[t] = v + add;
    __syncthreads();
  }
  int prefix = (t > 0) ? sums[t - 1] : 0;
  for (int i = beg; i < end; ++i) {
    int c = cnt[i];
    rowptr[i] = prefix;
    prefix += c;
    dinv[i] = rsqrtf((float)(c + 1));  // +1 self-loop
  }
  if (t == 1023) rowptr[N] = sums[1023];
}

__global__ void scatter_kernel(const int* __restrict__ ei, const int* __restrict__ flag,
                               const int* __restrict__ rowptr, int* __restrict__ fill,
                               int* __restrict__ col, int E) {
  int e = blockIdx.x * 256 + threadIdx.x;
  if (e >= E) return;
  int s, d;
  if (flag[0]) {
    const long long* e64 = (const long long*)ei;
    s = (int)e64[e];
    d = (int)e64[(size_t)E + e];
  } else {
    s = ei[e];
    d = ei[(size_t)E + e];
  }
  int pos = rowptr[d] + atomicAdd(&fill[d], 1);
  col[pos] = s;
}

// -------------------- bf16 conversion / weight packing --------------------

__global__ void cvt_x_kernel(const float* __restrict__ x, ushort* __restrict__ xb,
                             int n, int npad) {
  int i = blockIdx.x * 256 + threadIdx.x;
  if (i < n) xb[i] = f2bf(x[i]);
  else if (i < npad) xb[i] = 0;
}

// Wp layout: [K/32][16 colblk][64 lane][8 bf16], element (ks,cb,lane,i):
//   k = ks*32 + (lane>>4)*8 + i,  n = cb*16 + (lane&15)   (MFMA B-frag order)
__global__ void pack_w_kernel(const float* __restrict__ W, ushort* __restrict__ Wp, int K) {
  int idx = blockIdx.x * 256 + threadIdx.x;
  int total = (K >> 5) * 16 * 64;
  if (idx >= total) return;
  int lane = idx & 63;
  int cb = (idx >> 6) & 15;
  int ks = idx >> 10;
  int n = cb * 16 + (lane & 15);
  int kbase = ks * 32 + (lane >> 4) * 8;
#pragma unroll
  for (int i = 0; i < 8; ++i)
    Wp[(size_t)idx * 8 + i] = f2bf(W[(size_t)(kbase + i) * 256 + n]);
}

// -------------------- bf16 MFMA GEMM: C[M,256] = post(A[M,K] @ W) --------------------
// block = 256 thr (4 waves), tile 64 rows x 256 cols; wave w owns cols w*64..+63.
// Per wave: 4 rowblk x 4 colblk 16x16 frags, K-loop step 32.

__global__ __launch_bounds__(256) void gemm_mfma_kernel(
    const ushort* __restrict__ A,   // [Mpad,K] bf16 row-major
    const ushort* __restrict__ Wp,  // packed frags
    const float* __restrict__ bias, // [256] or null
    const float* __restrict__ scale,// [M] dinv or null (applied after bias/relu)
    ushort* __restrict__ C,         // [Mpad,256] bf16
    int M, int K, int relu) {
  int t = threadIdx.x;
  int lane = t & 63, wave = t >> 6;
  int l15 = lane & 15, lk = lane >> 4;
  int row0 = blockIdx.x * 64;

  f32x4 acc[4][4];
#pragma unroll
  for (int rb = 0; rb < 4; ++rb)
#pragma unroll
    for (int cb = 0; cb < 4; ++cb) acc[rb][cb] = (f32x4){0.f, 0.f, 0.f, 0.f};

  const ushort* abase[4];
#pragma unroll
  for (int rb = 0; rb < 4; ++rb)
    abase[rb] = A + (size_t)(row0 + rb * 16 + l15) * K + lk * 8;
  const ushort* bbase = Wp + ((size_t)(wave * 4) * 64 + lane) * 8;

  int nks = K >> 5;
  for (int ks = 0; ks < nks; ++ks) {
    bf16x8 a[4], b[4];
#pragma unroll
    for (int rb = 0; rb < 4; ++rb)
      a[rb] = *reinterpret_cast<const bf16x8*>(abase[rb] + ks * 32);
#pragma unroll
    for (int cb = 0; cb < 4; ++cb)
      b[cb] = *reinterpret_cast<const bf16x8*>(bbase + ((size_t)ks * 16 + cb) * 64 * 8);
#pragma unroll
    for (int rb = 0; rb < 4; ++rb)
#pragma unroll
      for (int cb = 0; cb < 4; ++cb)
        acc[rb][cb] = __builtin_amdgcn_mfma_f32_16x16x32_bf16(a[rb], b[cb], acc[rb][cb], 0, 0, 0);
  }

  float bv[4];
#pragma unroll
  for (int cb = 0; cb < 4; ++cb)
    bv[cb] = bias ? bias[wave * 64 + cb * 16 + l15] : 0.f;

#pragma unroll
  for (int rb = 0; rb < 4; ++rb) {
    int rbase = row0 + rb * 16 + lk * 4;
#pragma unroll
    for (int r = 0; r < 4; ++r) {
      int row = rbase + r;
      if (row >= M) continue;
      float sc = scale ? scale[row] : 1.f;
#pragma unroll
      for (int cb = 0; cb < 4; ++cb) {
        float v = acc[rb][cb][r] + bv[cb];
        if (relu) v = fmaxf(v, 0.f);
        v *= sc;
        C[(size_t)row * 256 + wave * 64 + cb * 16 + l15] = f2bf(v);
      }
    }
  }
}

// -------- message passing: h[n] = relu(dinv[n]*(sum_{s in in(n)} hw'[s] + hw'[n]) + b) ----
// hw' rows already scaled by dinv[src] in the GEMM epilogue.

__global__ __launch_bounds__(64) void mp_kernel(const ushort* __restrict__ hw,
                                                const int* __restrict__ rowptr,
                                                const int* __restrict__ col,
                                                const float* __restrict__ dinv,
                                                const float* __restrict__ bias,
                                                ushort* __restrict__ hout) {
  int n = blockIdx.x;
  int t = threadIdx.x;  // 64 lanes x 4 bf16 = 256 cols
  ushort4 sv = *reinterpret_cast<const ushort4*>(hw + (size_t)n * 256 + t * 4);
  float ax = bf2f(sv.x), ay = bf2f(sv.y), az = bf2f(sv.z), aw = bf2f(sv.w);  // self
  int beg = rowptr[n], end = rowptr[n + 1];
  for (int j = beg; j < end; ++j) {
    int s = col[j];
    ushort4 hv = *reinterpret_cast<const ushort4*>(hw + (size_t)s * 256 + t * 4);
    ax += bf2f(hv.x); ay += bf2f(hv.y); az += bf2f(hv.z); aw += bf2f(hv.w);
  }
  float dn = dinv[n];
  float4 bv = *reinterpret_cast<const float4*>(bias + t * 4);
  ushort4 o;
  o.x = f2bf(fmaxf(fmaf(dn, ax, bv.x), 0.f));
  o.y = f2bf(fmaxf(fmaf(dn, ay, bv.y), 0.f));
  o.z = f2bf(fmaxf(fmaf(dn, az, bv.z), 0.f));
  o.w = f2bf(fmaxf(fmaf(dn, aw, bv.w), 0.f));
  *reinterpret_cast<ushort4*>(hout + (size_t)n * 256 + t * 4) = o;
}

// -------------------- pooling: column-wise sum + max over N rows --------------------

__global__ __launch_bounds__(256) void pool_kernel(const ushort* __restrict__ h,
                                                   float* __restrict__ pooled_sum,
                                                   unsigned* __restrict__ pooled_max, int N) {
  int t = threadIdx.x;  // col
  int r0 = blockIdx.x * 250;
  int r1 = min(r0 + 250, N);
  float s = 0.f, m = 0.f;  // h >= 0 after relu
  for (int r = r0; r < r1; ++r) {
    float v = bf2f(h[(size_t)r * 256 + t]);
    s += v;
    m = fmaxf(m, v);
  }
  atomicAdd(&pooled_sum[t], s);
  atomicMax(&pooled_max[t], __float_as_uint(m));  // valid: non-negative floats
}

// -------------------- head: graph projection + decoder + scalar logit (f32) ------------

__global__ __launch_bounds__(256) void head_kernel(const float* __restrict__ pooled,
                                                   const float* __restrict__ Wg1, const float* __restrict__ bg1,
                                                   const float* __restrict__ Wg2, const float* __restrict__ bg2,
                                                   const float* __restrict__ Wd1, const float* __restrict__ bd1,
                                                   const float* __restrict__ Wd2, const float* __restrict__ bd2,
                                                   float* __restrict__ out_ge, float* __restrict__ s_out, int N) {
  __shared__ float gr[512];
  __shared__ float t1[256];
  __shared__ float ge[128];
  __shared__ float t2[256];
  __shared__ float v[256];
  __shared__ float red[4];
  int t = threadIdx.x;
  gr[t] = pooled[t] / (float)N;                                       // mean
  gr[256 + t] = __uint_as_float(((const unsigned*)pooled)[256 + t]);  // max (bit-stored)
  __syncthreads();
  float acc = bg1[t];
  for (int k = 0; k < 512; ++k) acc = fmaf(gr[k], Wg1[k * 256 + t], acc);
  t1[t] = fmaxf(acc, 0.f);
  __syncthreads();
  if (t < 128) {
    float a = bg2[t];
    for (int k = 0; k < 256; ++k) a = fmaf(t1[k], Wg2[k * 128 + t], a);
    ge[t] = a;
    out_ge[t] = a;  // output 0: graph_embedding
  }
  __syncthreads();
  acc = bd1[t];
  for (int k = 0; k < 128; ++k) acc = fmaf(ge[k], Wd1[k * 256 + t], acc);
  t2[t] = fmaxf(acc, 0.f);
  __syncthreads();
  acc = bd2[t];
  for (int k = 0; k < 256; ++k) acc = fmaf(t2[k], Wd2[k * 256 + t], acc);
  v[t] = acc;
  __syncthreads();
  float p = v[t] * v[t];
  for (int off = 32; off > 0; off >>= 1) p += __shfl_down(p, off, 64);
  if ((t & 63) == 0) red[t >> 6] = p;
  __syncthreads();
  if (t == 0) {
    float ssq = red[0] + red[1] + red[2] + red[3];
    s_out[0] = 1.f / (1.f + expf(-ssq));
  }
}

__global__ void fill_kernel(float* __restrict__ out, const float* __restrict__ s_out, int E) {
  int i = blockIdx.x * 256 + threadIdx.x;
  if (i < E) out[i] = s_out[0];
}

// -------------------- launch --------------------

extern "C" void kernel_launch(void* const* d_in, const int* in_sizes, int n_in,
                              void* d_out, int out_size, void* d_ws, size_t ws_size,
                              hipStream_t stream) {
  const float* x   = (const float*)d_in[0];
  const int*   ei  = (const int*)d_in[1];
  const float* W1  = (const float*)d_in[2];
  const float* b1  = (const float*)d_in[3];
  const float* W2  = (const float*)d_in[4];
  const float* b2  = (const float*)d_in[5];
  const float* cW  = (const float*)d_in[6];
  const float* cb  = (const float*)d_in[7];
  const float* Wg1 = (const float*)d_in[8];
  const float* bg1 = (const float*)d_in[9];
  const float* Wg2 = (const float*)d_in[10];
  const float* bg2 = (const float*)d_in[11];
  const float* Wd1 = (const float*)d_in[12];
  const float* bd1 = (const float*)d_in[13];
  const float* Wd2 = (const float*)d_in[14];
  const float* bd2 = (const float*)d_in[15];
  float* out = (float*)d_out;

  int N = in_sizes[0] / 64;  // 50000
  int E = in_sizes[1] / 2;   // 800000
  int Mpad = (N + 63) & ~63; // 50048

  size_t off = 0;
  auto walloc = [&](size_t bytes) -> void* {
    void* p = (char*)d_ws + off;
    off += (bytes + 511) & ~(size_t)511;
    return p;
  };
  ushort* hA    = (ushort*)walloc((size_t)Mpad * 256 * 2);
  ushort* hB    = (ushort*)walloc((size_t)Mpad * 256 * 2);
  ushort* xb    = (ushort*)walloc((size_t)Mpad * 64 * 2);
  ushort* Wp1   = (ushort*)walloc((size_t)2 * 16 * 64 * 8 * 2);
  ushort* Wp2   = (ushort*)walloc((size_t)8 * 16 * 64 * 8 * 2);
  ushort* Wpc   = (ushort*)walloc((size_t)3 * 8 * 16 * 64 * 8 * 2);
  int*   cnt    = (int*)walloc((size_t)N * 4);
  int*   fillc  = (int*)walloc((size_t)N * 4);
  int*   rowptr = (int*)walloc(((size_t)N + 1) * 4);
  float* dinv   = (float*)walloc((size_t)N * 4);
  int*   col    = (int*)walloc((size_t)E * 4);
  float* pooled = (float*)walloc(512 * 4);
  float* s_out  = (float*)walloc(512);
  int*   flag   = (int*)walloc(512);

  // graph structure (CSR by dst)
  detect_i64_kernel<<<1, 64, 0, stream>>>(ei, flag);
  init_kernel<<<(N + 255) / 256, 256, 0, stream>>>(cnt, fillc, pooled, N);
  count_kernel<<<(E + 255) / 256, 256, 0, stream>>>(ei, flag, cnt, E);
  scan_kernel<<<1, 1024, 0, stream>>>(cnt, rowptr, dinv, N);
  scatter_kernel<<<(E + 255) / 256, 256, 0, stream>>>(ei, flag, rowptr, fillc, col, E);

  // bf16 conversion + weight packing
  cvt_x_kernel<<<(Mpad * 64 + 255) / 256, 256, 0, stream>>>(x, xb, N * 64, Mpad * 64);
  pack_w_kernel<<<(2 * 16 * 64 + 255) / 256, 256, 0, stream>>>(W1, Wp1, 64);
  pack_w_kernel<<<(8 * 16 * 64 + 255) / 256, 256, 0, stream>>>(W2, Wp2, 256);
  for (int l = 0; l < 3; ++l)
    pack_w_kernel<<<(8 * 16 * 64 + 255) / 256, 256, 0, stream>>>(
        cW + (size_t)l * 256 * 256, Wpc + (size_t)l * 8 * 16 * 64 * 8, 256);

  int gblocks = Mpad / 64;
  // encoder
  gemm_mfma_kernel<<<gblocks, 256, 0, stream>>>(xb, Wp1, b1, nullptr, hA, N, 64, 1);
  gemm_mfma_kernel<<<gblocks, 256, 0, stream>>>(hA, Wp2, b2, nullptr, hB, N, 256, 0);
  // GCN layers: hw' = (h @ convW) * dinv[row]; h = relu(dinv*(gather+self) + b)
  for (int l = 0; l < 3; ++l) {
    gemm_mfma_kernel<<<gblocks, 256, 0, stream>>>(
        hB, Wpc + (size_t)l * 8 * 16 * 64 * 8, nullptr, dinv, hA, N, 256, 0);
    mp_kernel<<<N, 64, 0, stream>>>(hA, rowptr, col, dinv, cb + (size_t)l * 256, hB);
  }
  // readout
  pool_kernel<<<(N + 249) / 250, 256, 0, stream>>>(hB, pooled, (unsigned*)(pooled + 256), N);
  head_kernel<<<1, 256, 0, stream>>>(pooled, Wg1, bg1, Wg2, bg2, Wd1, bd1, Wd2, bd2, out, s_out, N);
  fill_kernel<<<(E + 255) / 256, 256, 0, stream>>>(out + 128, s_out, E);
}

// Round 3
// 528.726 us; speedup vs baseline: 2.1141x; 1.1741x over previous
//
#include <hip/hip_runtime.h>
#include <hip/hip_bf16.h>

// GAE forward, bf16 compute path.
//   CSR build (count / 3-phase multiblock scan / scatter)
//   -> cvt x->bf16, pack weights to MFMA frag order
//   -> 5x bf16-MFMA GEMM (encoder x2, conv x3; conv epilogue scales row by dinv)
//   -> 3x mp gather (bf16 rows, f32 accum) -> pool -> head (f32) -> fill(sigmoid const)
// edge_probs is constant: node_emb rows are the same broadcast vector v,
// so logit = sum(v*v) for every edge.

typedef __attribute__((ext_vector_type(8))) short bf16x8;
typedef __attribute__((ext_vector_type(4))) float f32x4;

__device__ __forceinline__ ushort f2bf(float f) {
  union { float f; unsigned u; } v; v.f = f;
  unsigned r = v.u + 0x7FFF + ((v.u >> 16) & 1);  // RNE
  return (ushort)(r >> 16);
}
__device__ __forceinline__ float bf2f(ushort b) {
  union { unsigned u; float f; } v; v.u = ((unsigned)b) << 16;
  return v.f;
}

// -------------------- CSR build --------------------

__global__ void detect_i64_kernel(const int* __restrict__ ei, int* __restrict__ flag) {
  if (threadIdx.x == 0 && blockIdx.x == 0) {
    int all0 = 1;
    for (int i = 0; i < 128; ++i) {
      if (ei[2 * i + 1] != 0) { all0 = 0; break; }
    }
    flag[0] = all0;  // 1 => int64 payload (high words all zero)
  }
}

__global__ void init_kernel(int* __restrict__ cnt, int* __restrict__ fill,
                            float* __restrict__ pooled, int N) {
  int i = blockIdx.x * 256 + threadIdx.x;
  if (i < N) { cnt[i] = 0; fill[i] = 0; }
  if (i < 512) pooled[i] = 0.f;  // sum[0:256]=0, max bits[256:512]=+0.0 (h>=0)
}

__global__ void count_kernel(const int* __restrict__ ei, const int* __restrict__ flag,
                             int* __restrict__ cnt, int E) {
  int e = blockIdx.x * 256 + threadIdx.x;
  if (e >= E) return;
  int d;
  if (flag[0]) d = (int)((const long long*)ei)[(size_t)E + e];
  else         d = ei[(size_t)E + e];
  atomicAdd(&cnt[d], 1);
}

// 3-phase multiblock exclusive scan over cnt[N] -> rowptr[N+1], plus dinv.

__global__ __launch_bounds__(256) void bsum_kernel(const int* __restrict__ cnt,
                                                   int* __restrict__ bsum, int N) {
  __shared__ int red[4];
  int t = threadIdx.x;
  int i = blockIdx.x * 256 + t;
  int v = (i < N) ? cnt[i] : 0;
  for (int off = 32; off > 0; off >>= 1) v += __shfl_down(v, off, 64);
  if ((t & 63) == 0) red[t >> 6] = v;
  __syncthreads();
  if (t == 0) bsum[blockIdx.x] = red[0] + red[1] + red[2] + red[3];
}

__global__ __launch_bounds__(256) void bscan_kernel(const int* __restrict__ bsum,
                                                    int* __restrict__ boff,
                                                    int* __restrict__ rowptr, int B, int N) {
  __shared__ int s[256];
  int t = threadIdx.x;
  int v = (t < B) ? bsum[t] : 0;
  s[t] = v;
  __syncthreads();
  for (int off = 1; off < 256; off <<= 1) {
    int x = s[t];
    int add = (t >= off) ? s[t - off] : 0;
    __syncthreads();
    s[t] = x + add;
    __syncthreads();
  }
  if (t < B) boff[t] = s[t] - v;  // exclusive block offset
  if (t == 255) rowptr[N] = s[255];
}

__global__ __launch_bounds__(256) void rowptr_kernel(const int* __restrict__ cnt,
                                                     const int* __restrict__ boff,
                                                     int* __restrict__ rowptr,
                                                     float* __restrict__ dinv, int N) {
  __shared__ int s[256];
  int t = threadIdx.x;
  int i = blockIdx.x * 256 + t;
  int v = (i < N) ? cnt[i] : 0;
  s[t] = v;
  __syncthreads();
  for (int off = 1; off < 256; off <<= 1) {
    int x = s[t];
    int add = (t >= off) ? s[t - off] : 0;
    __syncthreads();
    s[t] = x + add;
    __syncthreads();
  }
  if (i < N) {
    rowptr[i] = boff[blockIdx.x] + s[t] - v;
    dinv[i] = rsqrtf((float)(v + 1));  // +1 self-loop
  }
}

__global__ void scatter_kernel(const int* __restrict__ ei, const int* __restrict__ flag,
                               const int* __restrict__ rowptr, int* __restrict__ fill,
                               int* __restrict__ col, int E) {
  int e = blockIdx.x * 256 + threadIdx.x;
  if (e >= E) return;
  int s, d;
  if (flag[0]) {
    const long long* e64 = (const long long*)ei;
    s = (int)e64[e];
    d = (int)e64[(size_t)E + e];
  } else {
    s = ei[e];
    d = ei[(size_t)E + e];
  }
  int pos = rowptr[d] + atomicAdd(&fill[d], 1);
  col[pos] = s;
}

// -------------------- bf16 conversion / weight packing --------------------

__global__ void cvt_x_kernel(const float* __restrict__ x, ushort* __restrict__ xb,
                             int n, int npad) {
  int i = blockIdx.x * 256 + threadIdx.x;
  if (i < n) xb[i] = f2bf(x[i]);
  else if (i < npad) xb[i] = 0;
}

// Wp layout: [K/32][16 colblk][64 lane][8 bf16], element (ks,cb,lane,i):
//   k = ks*32 + (lane>>4)*8 + i,  n = cb*16 + (lane&15)   (MFMA B-frag order)
__global__ void pack_w_kernel(const float* __restrict__ W, ushort* __restrict__ Wp, int K) {
  int idx = blockIdx.x * 256 + threadIdx.x;
  int total = (K >> 5) * 16 * 64;
  if (idx >= total) return;
  int lane = idx & 63;
  int cb = (idx >> 6) & 15;
  int ks = idx >> 10;
  int n = cb * 16 + (lane & 15);
  int kbase = ks * 32 + (lane >> 4) * 8;
#pragma unroll
  for (int i = 0; i < 8; ++i)
    Wp[(size_t)idx * 8 + i] = f2bf(W[(size_t)(kbase + i) * 256 + n]);
}

// -------------------- bf16 MFMA GEMM: C[M,256] = post(A[M,K] @ W) --------------------
// block = 256 thr (4 waves), tile 64 rows x 256 cols; wave w owns cols w*64..+63.
// Per wave: 4 rowblk x 4 colblk 16x16 frags, K-loop step 32.

__global__ __launch_bounds__(256) void gemm_mfma_kernel(
    const ushort* __restrict__ A,   // [Mpad,K] bf16 row-major
    const ushort* __restrict__ Wp,  // packed frags
    const float* __restrict__ bias, // [256] or null
    const float* __restrict__ scale,// [M] dinv or null (applied after bias/relu)
    ushort* __restrict__ C,         // [Mpad,256] bf16
    int M, int K, int relu) {
  int t = threadIdx.x;
  int lane = t & 63, wave = t >> 6;
  int l15 = lane & 15, lk = lane >> 4;
  int row0 = blockIdx.x * 64;

  f32x4 acc[4][4];
#pragma unroll
  for (int rb = 0; rb < 4; ++rb)
#pragma unroll
    for (int cb = 0; cb < 4; ++cb) acc[rb][cb] = (f32x4){0.f, 0.f, 0.f, 0.f};

  const ushort* abase[4];
#pragma unroll
  for (int rb = 0; rb < 4; ++rb)
    abase[rb] = A + (size_t)(row0 + rb * 16 + l15) * K + lk * 8;
  const ushort* bbase = Wp + ((size_t)(wave * 4) * 64 + lane) * 8;

  int nks = K >> 5;
  for (int ks = 0; ks < nks; ++ks) {
    bf16x8 a[4], b[4];
#pragma unroll
    for (int rb = 0; rb < 4; ++rb)
      a[rb] = *reinterpret_cast<const bf16x8*>(abase[rb] + ks * 32);
#pragma unroll
    for (int cb = 0; cb < 4; ++cb)
      b[cb] = *reinterpret_cast<const bf16x8*>(bbase + ((size_t)ks * 16 + cb) * 64 * 8);
#pragma unroll
    for (int rb = 0; rb < 4; ++rb)
#pragma unroll
      for (int cb = 0; cb < 4; ++cb)
        acc[rb][cb] = __builtin_amdgcn_mfma_f32_16x16x32_bf16(a[rb], b[cb], acc[rb][cb], 0, 0, 0);
  }

  float bv[4];
#pragma unroll
  for (int cb = 0; cb < 4; ++cb)
    bv[cb] = bias ? bias[wave * 64 + cb * 16 + l15] : 0.f;

#pragma unroll
  for (int rb = 0; rb < 4; ++rb) {
    int rbase = row0 + rb * 16 + lk * 4;
#pragma unroll
    for (int r = 0; r < 4; ++r) {
      int row = rbase + r;
      if (row >= M) continue;
      float sc = scale ? scale[row] : 1.f;
#pragma unroll
      for (int cb = 0; cb < 4; ++cb) {
        float v = acc[rb][cb][r] + bv[cb];
        if (relu) v = fmaxf(v, 0.f);
        v *= sc;
        C[(size_t)row * 256 + wave * 64 + cb * 16 + l15] = f2bf(v);
      }
    }
  }
}

// -------- message passing: h[n] = relu(dinv[n]*(sum_{s in in(n)} hw'[s] + hw'[n]) + b) ----
// hw' rows already scaled by dinv[src] in the GEMM epilogue.

__global__ __launch_bounds__(64) void mp_kernel(const ushort* __restrict__ hw,
                                                const int* __restrict__ rowptr,
                                                const int* __restrict__ col,
                                                const float* __restrict__ dinv,
                                                const float* __restrict__ bias,
                                                ushort* __restrict__ hout) {
  int n = blockIdx.x;
  int t = threadIdx.x;  // 64 lanes x 4 bf16 = 256 cols
  ushort4 sv = *reinterpret_cast<const ushort4*>(hw + (size_t)n * 256 + t * 4);
  float ax = bf2f(sv.x), ay = bf2f(sv.y), az = bf2f(sv.z), aw = bf2f(sv.w);  // self
  int beg = rowptr[n], end = rowptr[n + 1];
  for (int j = beg; j < end; ++j) {
    int s = col[j];
    ushort4 hv = *reinterpret_cast<const ushort4*>(hw + (size_t)s * 256 + t * 4);
    ax += bf2f(hv.x); ay += bf2f(hv.y); az += bf2f(hv.z); aw += bf2f(hv.w);
  }
  float dn = dinv[n];
  float4 bv = *reinterpret_cast<const float4*>(bias + t * 4);
  ushort4 o;
  o.x = f2bf(fmaxf(fmaf(dn, ax, bv.x), 0.f));
  o.y = f2bf(fmaxf(fmaf(dn, ay, bv.y), 0.f));
  o.z = f2bf(fmaxf(fmaf(dn, az, bv.z), 0.f));
  o.w = f2bf(fmaxf(fmaf(dn, aw, bv.w), 0.f));
  *reinterpret_cast<ushort4*>(hout + (size_t)n * 256 + t * 4) = o;
}

// -------------------- pooling: column-wise sum + max over N rows --------------------

__global__ __launch_bounds__(256) void pool_kernel(const ushort* __restrict__ h,
                                                   float* __restrict__ pooled_sum,
                                                   unsigned* __restrict__ pooled_max, int N) {
  int t = threadIdx.x;  // col
  int r0 = blockIdx.x * 250;
  int r1 = min(r0 + 250, N);
  float s = 0.f, m = 0.f;  // h >= 0 after relu
  for (int r = r0; r < r1; ++r) {
    float v = bf2f(h[(size_t)r * 256 + t]);
    s += v;
    m = fmaxf(m, v);
  }
  atomicAdd(&pooled_sum[t], s);
  atomicMax(&pooled_max[t], __float_as_uint(m));  // valid: non-negative floats
}

// -------------------- head: graph projection + decoder + scalar logit (f32) ------------

__global__ __launch_bounds__(256) void head_kernel(const float* __restrict__ pooled,
                                                   const float* __restrict__ Wg1, const float* __restrict__ bg1,
                                                   const float* __restrict__ Wg2, const float* __restrict__ bg2,
                                                   const float* __restrict__ Wd1, const float* __restrict__ bd1,
                                                   const float* __restrict__ Wd2, const float* __restrict__ bd2,
                                                   float* __restrict__ out_ge, float* __restrict__ s_out, int N) {
  __shared__ float gr[512];
  __shared__ float t1[256];
  __shared__ float ge[128];
  __shared__ float t2[256];
  __shared__ float v[256];
  __shared__ float red[4];
  int t = threadIdx.x;
  gr[t] = pooled[t] / (float)N;                                       // mean
  gr[256 + t] = __uint_as_float(((const unsigned*)pooled)[256 + t]);  // max (bit-stored)
  __syncthreads();
  float acc = bg1[t];
  for (int k = 0; k < 512; ++k) acc = fmaf(gr[k], Wg1[k * 256 + t], acc);
  t1[t] = fmaxf(acc, 0.f);
  __syncthreads();
  if (t < 128) {
    float a = bg2[t];
    for (int k = 0; k < 256; ++k) a = fmaf(t1[k], Wg2[k * 128 + t], a);
    ge[t] = a;
    out_ge[t] = a;  // output 0: graph_embedding
  }
  __syncthreads();
  acc = bd1[t];
  for (int k = 0; k < 128; ++k) acc = fmaf(ge[k], Wd1[k * 256 + t], acc);
  t2[t] = fmaxf(acc, 0.f);
  __syncthreads();
  acc = bd2[t];
  for (int k = 0; k < 256; ++k) acc = fmaf(t2[k], Wd2[k * 256 + t], acc);
  v[t] = acc;
  __syncthreads();
  float p = v[t] * v[t];
  for (int off = 32; off > 0; off >>= 1) p += __shfl_down(p, off, 64);
  if ((t & 63) == 0) red[t >> 6] = p;
  __syncthreads();
  if (t == 0) {
    float ssq = red[0] + red[1] + red[2] + red[3];
    s_out[0] = 1.f / (1.f + expf(-ssq));
  }
}

__global__ void fill_kernel(float* __restrict__ out, const float* __restrict__ s_out, int E) {
  int i = blockIdx.x * 256 + threadIdx.x;
  if (i < E) out[i] = s_out[0];
}

// -------------------- launch --------------------

extern "C" void kernel_launch(void* const* d_in, const int* in_sizes, int n_in,
                              void* d_out, int out_size, void* d_ws, size_t ws_size,
                              hipStream_t stream) {
  const float* x   = (const float*)d_in[0];
  const int*   ei  = (const int*)d_in[1];
  const float* W1  = (const float*)d_in[2];
  const float* b1  = (const float*)d_in[3];
  const float* W2  = (const float*)d_in[4];
  const float* b2  = (const float*)d_in[5];
  const float* cW  = (const float*)d_in[6];
  const float* cb  = (const float*)d_in[7];
  const float* Wg1 = (const float*)d_in[8];
  const float* bg1 = (const float*)d_in[9];
  const float* Wg2 = (const float*)d_in[10];
  const float* bg2 = (const float*)d_in[11];
  const float* Wd1 = (const float*)d_in[12];
  const float* bd1 = (const float*)d_in[13];
  const float* Wd2 = (const float*)d_in[14];
  const float* bd2 = (const float*)d_in[15];
  float* out = (float*)d_out;

  int N = in_sizes[0] / 64;  // 50000
  int E = in_sizes[1] / 2;   // 800000
  int Mpad = (N + 63) & ~63; // 50048
  int B = (N + 255) / 256;   // scan blocks (196)

  size_t off = 0;
  auto walloc = [&](size_t bytes) -> void* {
    void* p = (char*)d_ws + off;
    off += (bytes + 511) & ~(size_t)511;
    return p;
  };
  ushort* hA    = (ushort*)walloc((size_t)Mpad * 256 * 2);
  ushort* hB    = (ushort*)walloc((size_t)Mpad * 256 * 2);
  ushort* xb    = (ushort*)walloc((size_t)Mpad * 64 * 2);
  ushort* Wp1   = (ushort*)walloc((size_t)2 * 16 * 64 * 8 * 2);
  ushort* Wp2   = (ushort*)walloc((size_t)8 * 16 * 64 * 8 * 2);
  ushort* Wpc   = (ushort*)walloc((size_t)3 * 8 * 16 * 64 * 8 * 2);
  int*   cnt    = (int*)walloc((size_t)N * 4);
  int*   fillc  = (int*)walloc((size_t)N * 4);
  int*   rowptr = (int*)walloc(((size_t)N + 1) * 4);
  float* dinv   = (float*)walloc((size_t)N * 4);
  int*   col    = (int*)walloc((size_t)E * 4);
  int*   bsum   = (int*)walloc(256 * 4);
  int*   boff   = (int*)walloc(256 * 4);
  float* pooled = (float*)walloc(512 * 4);
  float* s_out  = (float*)walloc(512);
  int*   flag   = (int*)walloc(512);

  // graph structure (CSR by dst)
  detect_i64_kernel<<<1, 64, 0, stream>>>(ei, flag);
  init_kernel<<<(N + 255) / 256, 256, 0, stream>>>(cnt, fillc, pooled, N);
  count_kernel<<<(E + 255) / 256, 256, 0, stream>>>(ei, flag, cnt, E);
  bsum_kernel<<<B, 256, 0, stream>>>(cnt, bsum, N);
  bscan_kernel<<<1, 256, 0, stream>>>(bsum, boff, rowptr, B, N);
  rowptr_kernel<<<B, 256, 0, stream>>>(cnt, boff, rowptr, dinv, N);
  scatter_kernel<<<(E + 255) / 256, 256, 0, stream>>>(ei, flag, rowptr, fillc, col, E);

  // bf16 conversion + weight packing
  cvt_x_kernel<<<(Mpad * 64 + 255) / 256, 256, 0, stream>>>(x, xb, N * 64, Mpad * 64);
  pack_w_kernel<<<(2 * 16 * 64 + 255) / 256, 256, 0, stream>>>(W1, Wp1, 64);
  pack_w_kernel<<<(8 * 16 * 64 + 255) / 256, 256, 0, stream>>>(W2, Wp2, 256);
  for (int l = 0; l < 3; ++l)
    pack_w_kernel<<<(8 * 16 * 64 + 255) / 256, 256, 0, stream>>>(
        cW + (size_t)l * 256 * 256, Wpc + (size_t)l * 8 * 16 * 64 * 8, 256);

  int gblocks = Mpad / 64;
  // encoder
  gemm_mfma_kernel<<<gblocks, 256, 0, stream>>>(xb, Wp1, b1, nullptr, hA, N, 64, 1);
  gemm_mfma_kernel<<<gblocks, 256, 0, stream>>>(hA, Wp2, b2, nullptr, hB, N, 256, 0);
  // GCN layers: hw' = (h @ convW) * dinv[row]; h = relu(dinv*(gather+self) + b)
  for (int l = 0; l < 3; ++l) {
    gemm_mfma_kernel<<<gblocks, 256, 0, stream>>>(
        hB, Wpc + (size_t)l * 8 * 16 * 64 * 8, nullptr, dinv, hA, N, 256, 0);
    mp_kernel<<<N, 64, 0, stream>>>(hA, rowptr, col, dinv, cb + (size_t)l * 256, hB);
  }
  // readout
  pool_kernel<<<(N + 249) / 250, 256, 0, stream>>>(hB, pooled, (unsigned*)(pooled + 256), N);
  head_kernel<<<1, 256, 0, stream>>>(pooled, Wg1, bg1, Wg2, bg2, Wd1, bd1, Wd2, bd2, out, s_out, N);
  fill_kernel<<<(E + 255) / 256, 256, 0, stream>>>(out + 128, s_out, E);
}

// Round 4
// 508.665 us; speedup vs baseline: 2.1975x; 1.0394x over previous
//
#include <hip/hip_runtime.h>
#include <hip/hip_bf16.h>

// GAE forward, bf16 compute path.
//   CSR build (count / 3-phase multiblock scan / scatter)
//   -> cvt x->bf16, pack weights to MFMA frag order
//   -> 5x bf16-MFMA GEMM (encoder x2, conv x3; conv epilogue scales row by dinv)
//   -> 3x mp gather (bf16 rows, f32 accum) -> grid-strided pool -> head (f32)
//   -> fill(sigmoid const)
// edge_probs is constant: node_emb rows are the same broadcast vector v,
// so logit = sum(v*v) for every edge.

typedef __attribute__((ext_vector_type(8))) short bf16x8;
typedef __attribute__((ext_vector_type(4))) float f32x4;

__device__ __forceinline__ ushort f2bf(float f) {
  union { float f; unsigned u; } v; v.f = f;
  unsigned r = v.u + 0x7FFF + ((v.u >> 16) & 1);  // RNE
  return (ushort)(r >> 16);
}
__device__ __forceinline__ float bf2f(ushort b) {
  union { unsigned u; float f; } v; v.u = ((unsigned)b) << 16;
  return v.f;
}

// -------------------- CSR build --------------------

__global__ void detect_i64_kernel(const int* __restrict__ ei, int* __restrict__ flag) {
  if (threadIdx.x == 0 && blockIdx.x == 0) {
    int all0 = 1;
    for (int i = 0; i < 128; ++i) {
      if (ei[2 * i + 1] != 0) { all0 = 0; break; }
    }
    flag[0] = all0;  // 1 => int64 payload (high words all zero)
  }
}

__global__ void init_kernel(int* __restrict__ cnt, int* __restrict__ fill,
                            float* __restrict__ pooled, int N) {
  int i = blockIdx.x * 256 + threadIdx.x;
  if (i < N) { cnt[i] = 0; fill[i] = 0; }
  if (i < 512) pooled[i] = 0.f;  // sum[0:256]=0, max bits[256:512]=+0.0 (h>=0)
}

__global__ void count_kernel(const int* __restrict__ ei, const int* __restrict__ flag,
                             int* __restrict__ cnt, int E) {
  int e = blockIdx.x * 256 + threadIdx.x;
  if (e >= E) return;
  int d;
  if (flag[0]) d = (int)((const long long*)ei)[(size_t)E + e];
  else         d = ei[(size_t)E + e];
  atomicAdd(&cnt[d], 1);
}

// 3-phase multiblock exclusive scan over cnt[N] -> rowptr[N+1], plus dinv.

__global__ __launch_bounds__(256) void bsum_kernel(const int* __restrict__ cnt,
                                                   int* __restrict__ bsum, int N) {
  __shared__ int red[4];
  int t = threadIdx.x;
  int i = blockIdx.x * 256 + t;
  int v = (i < N) ? cnt[i] : 0;
  for (int off = 32; off > 0; off >>= 1) v += __shfl_down(v, off, 64);
  if ((t & 63) == 0) red[t >> 6] = v;
  __syncthreads();
  if (t == 0) bsum[blockIdx.x] = red[0] + red[1] + red[2] + red[3];
}

__global__ __launch_bounds__(256) void bscan_kernel(const int* __restrict__ bsum,
                                                    int* __restrict__ boff,
                                                    int* __restrict__ rowptr, int B, int N) {
  __shared__ int s[256];
  int t = threadIdx.x;
  int v = (t < B) ? bsum[t] : 0;
  s[t] = v;
  __syncthreads();
  for (int off = 1; off < 256; off <<= 1) {
    int x = s[t];
    int add = (t >= off) ? s[t - off] : 0;
    __syncthreads();
    s[t] = x + add;
    __syncthreads();
  }
  if (t < B) boff[t] = s[t] - v;  // exclusive block offset
  if (t == 255) rowptr[N] = s[255];
}

__global__ __launch_bounds__(256) void rowptr_kernel(const int* __restrict__ cnt,
                                                     const int* __restrict__ boff,
                                                     int* __restrict__ rowptr,
                                                     float* __restrict__ dinv, int N) {
  __shared__ int s[256];
  int t = threadIdx.x;
  int i = blockIdx.x * 256 + t;
  int v = (i < N) ? cnt[i] : 0;
  s[t] = v;
  __syncthreads();
  for (int off = 1; off < 256; off <<= 1) {
    int x = s[t];
    int add = (t >= off) ? s[t - off] : 0;
    __syncthreads();
    s[t] = x + add;
    __syncthreads();
  }
  if (i < N) {
    rowptr[i] = boff[blockIdx.x] + s[t] - v;
    dinv[i] = rsqrtf((float)(v + 1));  // +1 self-loop
  }
}

__global__ void scatter_kernel(const int* __restrict__ ei, const int* __restrict__ flag,
                               const int* __restrict__ rowptr, int* __restrict__ fill,
                               int* __restrict__ col, int E) {
  int e = blockIdx.x * 256 + threadIdx.x;
  if (e >= E) return;
  int s, d;
  if (flag[0]) {
    const long long* e64 = (const long long*)ei;
    s = (int)e64[e];
    d = (int)e64[(size_t)E + e];
  } else {
    s = ei[e];
    d = ei[(size_t)E + e];
  }
  int pos = rowptr[d] + atomicAdd(&fill[d], 1);
  col[pos] = s;
}

// -------------------- bf16 conversion / weight packing --------------------

__global__ void cvt_x_kernel(const float* __restrict__ x, ushort* __restrict__ xb,
                             int n, int npad) {
  int i = blockIdx.x * 256 + threadIdx.x;
  if (i < n) xb[i] = f2bf(x[i]);
  else if (i < npad) xb[i] = 0;
}

// Wp layout: [K/32][16 colblk][64 lane][8 bf16], element (ks,cb,lane,i):
//   k = ks*32 + (lane>>4)*8 + i,  n = cb*16 + (lane&15)   (MFMA B-frag order)
__global__ void pack_w_kernel(const float* __restrict__ W, ushort* __restrict__ Wp, int K) {
  int idx = blockIdx.x * 256 + threadIdx.x;
  int total = (K >> 5) * 16 * 64;
  if (idx >= total) return;
  int lane = idx & 63;
  int cb = (idx >> 6) & 15;
  int ks = idx >> 10;
  int n = cb * 16 + (lane & 15);
  int kbase = ks * 32 + (lane >> 4) * 8;
#pragma unroll
  for (int i = 0; i < 8; ++i)
    Wp[(size_t)idx * 8 + i] = f2bf(W[(size_t)(kbase + i) * 256 + n]);
}

// -------------------- bf16 MFMA GEMM: C[M,256] = post(A[M,K] @ W) --------------------
// block = 256 thr (4 waves), tile 64 rows x 256 cols; wave w owns cols w*64..+63.
// Per wave: 4 rowblk x 4 colblk 16x16 frags, K-loop step 32.

__global__ __launch_bounds__(256) void gemm_mfma_kernel(
    const ushort* __restrict__ A,   // [Mpad,K] bf16 row-major
    const ushort* __restrict__ Wp,  // packed frags
    const float* __restrict__ bias, // [256] or null
    const float* __restrict__ scale,// [M] dinv or null (applied after bias/relu)
    ushort* __restrict__ C,         // [Mpad,256] bf16
    int M, int K, int relu) {
  int t = threadIdx.x;
  int lane = t & 63, wave = t >> 6;
  int l15 = lane & 15, lk = lane >> 4;
  int row0 = blockIdx.x * 64;

  f32x4 acc[4][4];
#pragma unroll
  for (int rb = 0; rb < 4; ++rb)
#pragma unroll
    for (int cb = 0; cb < 4; ++cb) acc[rb][cb] = (f32x4){0.f, 0.f, 0.f, 0.f};

  const ushort* abase[4];
#pragma unroll
  for (int rb = 0; rb < 4; ++rb)
    abase[rb] = A + (size_t)(row0 + rb * 16 + l15) * K + lk * 8;
  const ushort* bbase = Wp + ((size_t)(wave * 4) * 64 + lane) * 8;

  int nks = K >> 5;
  for (int ks = 0; ks < nks; ++ks) {
    bf16x8 a[4], b[4];
#pragma unroll
    for (int rb = 0; rb < 4; ++rb)
      a[rb] = *reinterpret_cast<const bf16x8*>(abase[rb] + ks * 32);
#pragma unroll
    for (int cb = 0; cb < 4; ++cb)
      b[cb] = *reinterpret_cast<const bf16x8*>(bbase + ((size_t)ks * 16 + cb) * 64 * 8);
#pragma unroll
    for (int rb = 0; rb < 4; ++rb)
#pragma unroll
      for (int cb = 0; cb < 4; ++cb)
        acc[rb][cb] = __builtin_amdgcn_mfma_f32_16x16x32_bf16(a[rb], b[cb], acc[rb][cb], 0, 0, 0);
  }

  float bv[4];
#pragma unroll
  for (int cb = 0; cb < 4; ++cb)
    bv[cb] = bias ? bias[wave * 64 + cb * 16 + l15] : 0.f;

#pragma unroll
  for (int rb = 0; rb < 4; ++rb) {
    int rbase = row0 + rb * 16 + lk * 4;
#pragma unroll
    for (int r = 0; r < 4; ++r) {
      int row = rbase + r;
      if (row >= M) continue;
      float sc = scale ? scale[row] : 1.f;
#pragma unroll
      for (int cb = 0; cb < 4; ++cb) {
        float v = acc[rb][cb][r] + bv[cb];
        if (relu) v = fmaxf(v, 0.f);
        v *= sc;
        C[(size_t)row * 256 + wave * 64 + cb * 16 + l15] = f2bf(v);
      }
    }
  }
}

// -------- message passing: h[n] = relu(dinv[n]*(sum_{s in in(n)} hw'[s] + hw'[n]) + b) ----
// hw' rows already scaled by dinv[src] in the GEMM epilogue.

__global__ __launch_bounds__(64) void mp_kernel(const ushort* __restrict__ hw,
                                                const int* __restrict__ rowptr,
                                                const int* __restrict__ col,
                                                const float* __restrict__ dinv,
                                                const float* __restrict__ bias,
                                                ushort* __restrict__ hout) {
  int n = blockIdx.x;
  int t = threadIdx.x;  // 64 lanes x 4 bf16 = 256 cols
  ushort4 sv = *reinterpret_cast<const ushort4*>(hw + (size_t)n * 256 + t * 4);
  float ax = bf2f(sv.x), ay = bf2f(sv.y), az = bf2f(sv.z), aw = bf2f(sv.w);  // self
  int beg = rowptr[n], end = rowptr[n + 1];
  for (int j = beg; j < end; ++j) {
    int s = col[j];
    ushort4 hv = *reinterpret_cast<const ushort4*>(hw + (size_t)s * 256 + t * 4);
    ax += bf2f(hv.x); ay += bf2f(hv.y); az += bf2f(hv.z); aw += bf2f(hv.w);
  }
  float dn = dinv[n];
  float4 bv = *reinterpret_cast<const float4*>(bias + t * 4);
  ushort4 o;
  o.x = f2bf(fmaxf(fmaf(dn, ax, bv.x), 0.f));
  o.y = f2bf(fmaxf(fmaf(dn, ay, bv.y), 0.f));
  o.z = f2bf(fmaxf(fmaf(dn, az, bv.z), 0.f));
  o.w = f2bf(fmaxf(fmaf(dn, aw, bv.w), 0.f));
  *reinterpret_cast<ushort4*>(hout + (size_t)n * 256 + t * 4) = o;
}

// ---------- pooling: column sum+max over N rows, grid-strided 2-level reduce ----------
// Per iteration a block consumes 4 rows (wave w -> row, lane l -> cols 4l..4l+3,
// ushort4 = 8B/lane coalesced). LDS-reduce across waves, then 1 atomic/col/block.

__global__ __launch_bounds__(256) void pool_kernel(const ushort* __restrict__ h,
                                                   float* __restrict__ pooled_sum,
                                                   unsigned* __restrict__ pooled_max, int N) {
  __shared__ float ssum[4][256];
  __shared__ float smax[4][256];
  int t = threadIdx.x;
  int w = t >> 6, l = t & 63;
  int stride = gridDim.x * 4;
  float s0 = 0.f, s1 = 0.f, s2 = 0.f, s3 = 0.f;
  float m0 = 0.f, m1 = 0.f, m2 = 0.f, m3 = 0.f;  // h >= 0 after relu
  for (int r = blockIdx.x * 4 + w; r < N; r += stride) {
    ushort4 hv = *reinterpret_cast<const ushort4*>(h + (size_t)r * 256 + l * 4);
    float v0 = bf2f(hv.x), v1 = bf2f(hv.y), v2 = bf2f(hv.z), v3 = bf2f(hv.w);
    s0 += v0; s1 += v1; s2 += v2; s3 += v3;
    m0 = fmaxf(m0, v0); m1 = fmaxf(m1, v1); m2 = fmaxf(m2, v2); m3 = fmaxf(m3, v3);
  }
  ssum[w][l * 4] = s0; ssum[w][l * 4 + 1] = s1; ssum[w][l * 4 + 2] = s2; ssum[w][l * 4 + 3] = s3;
  smax[w][l * 4] = m0; smax[w][l * 4 + 1] = m1; smax[w][l * 4 + 2] = m2; smax[w][l * 4 + 3] = m3;
  __syncthreads();
  if (w == 0) {
#pragma unroll
    for (int j = 0; j < 4; ++j) {
      int c = l * 4 + j;
      float s = ssum[0][c] + ssum[1][c] + ssum[2][c] + ssum[3][c];
      float m = fmaxf(fmaxf(smax[0][c], smax[1][c]), fmaxf(smax[2][c], smax[3][c]));
      atomicAdd(&pooled_sum[c], s);
      atomicMax(&pooled_max[c], __float_as_uint(m));  // valid: non-negative floats
    }
  }
}

// -------------------- head: graph projection + decoder + scalar logit (f32) ------------

__global__ __launch_bounds__(256) void head_kernel(const float* __restrict__ pooled,
                                                   const float* __restrict__ Wg1, const float* __restrict__ bg1,
                                                   const float* __restrict__ Wg2, const float* __restrict__ bg2,
                                                   const float* __restrict__ Wd1, const float* __restrict__ bd1,
                                                   const float* __restrict__ Wd2, const float* __restrict__ bd2,
                                                   float* __restrict__ out_ge, float* __restrict__ s_out, int N) {
  __shared__ float gr[512];
  __shared__ float t1[256];
  __shared__ float ge[128];
  __shared__ float t2[256];
  __shared__ float v[256];
  __shared__ float red[4];
  int t = threadIdx.x;
  gr[t] = pooled[t] / (float)N;                                       // mean
  gr[256 + t] = __uint_as_float(((const unsigned*)pooled)[256 + t]);  // max (bit-stored)
  __syncthreads();
  float acc = bg1[t];
  for (int k = 0; k < 512; ++k) acc = fmaf(gr[k], Wg1[k * 256 + t], acc);
  t1[t] = fmaxf(acc, 0.f);
  __syncthreads();
  if (t < 128) {
    float a = bg2[t];
    for (int k = 0; k < 256; ++k) a = fmaf(t1[k], Wg2[k * 128 + t], a);
    ge[t] = a;
    out_ge[t] = a;  // output 0: graph_embedding
  }
  __syncthreads();
  acc = bd1[t];
  for (int k = 0; k < 128; ++k) acc = fmaf(ge[k], Wd1[k * 256 + t], acc);
  t2[t] = fmaxf(acc, 0.f);
  __syncthreads();
  acc = bd2[t];
  for (int k = 0; k < 256; ++k) acc = fmaf(t2[k], Wd2[k * 256 + t], acc);
  v[t] = acc;
  __syncthreads();
  float p = v[t] * v[t];
  for (int off = 32; off > 0; off >>= 1) p += __shfl_down(p, off, 64);
  if ((t & 63) == 0) red[t >> 6] = p;
  __syncthreads();
  if (t == 0) {
    float ssq = red[0] + red[1] + red[2] + red[3];
    s_out[0] = 1.f / (1.f + expf(-ssq));
  }
}

__global__ void fill_kernel(float* __restrict__ out, const float* __restrict__ s_out, int E) {
  int i = blockIdx.x * 256 + threadIdx.x;
  if (i < E) out[i] = s_out[0];
}

// -------------------- launch --------------------

extern "C" void kernel_launch(void* const* d_in, const int* in_sizes, int n_in,
                              void* d_out, int out_size, void* d_ws, size_t ws_size,
                              hipStream_t stream) {
  const float* x   = (const float*)d_in[0];
  const int*   ei  = (const int*)d_in[1];
  const float* W1  = (const float*)d_in[2];
  const float* b1  = (const float*)d_in[3];
  const float* W2  = (const float*)d_in[4];
  const float* b2  = (const float*)d_in[5];
  const float* cW  = (const float*)d_in[6];
  const float* cb  = (const float*)d_in[7];
  const float* Wg1 = (const float*)d_in[8];
  const float* bg1 = (const float*)d_in[9];
  const float* Wg2 = (const float*)d_in[10];
  const float* bg2 = (const float*)d_in[11];
  const float* Wd1 = (const float*)d_in[12];
  const float* bd1 = (const float*)d_in[13];
  const float* Wd2 = (const float*)d_in[14];
  const float* bd2 = (const float*)d_in[15];
  float* out = (float*)d_out;

  int N = in_sizes[0] / 64;  // 50000
  int E = in_sizes[1] / 2;   // 800000
  int Mpad = (N + 63) & ~63; // 50048
  int B = (N + 255) / 256;   // scan blocks (196)

  size_t off = 0;
  auto walloc = [&](size_t bytes) -> void* {
    void* p = (char*)d_ws + off;
    off += (bytes + 511) & ~(size_t)511;
    return p;
  };
  ushort* hA    = (ushort*)walloc((size_t)Mpad * 256 * 2);
  ushort* hB    = (ushort*)walloc((size_t)Mpad * 256 * 2);
  ushort* xb    = (ushort*)walloc((size_t)Mpad * 64 * 2);
  ushort* Wp1   = (ushort*)walloc((size_t)2 * 16 * 64 * 8 * 2);
  ushort* Wp2   = (ushort*)walloc((size_t)8 * 16 * 64 * 8 * 2);
  ushort* Wpc   = (ushort*)walloc((size_t)3 * 8 * 16 * 64 * 8 * 2);
  int*   cnt    = (int*)walloc((size_t)N * 4);
  int*   fillc  = (int*)walloc((size_t)N * 4);
  int*   rowptr = (int*)walloc(((size_t)N + 1) * 4);
  float* dinv   = (float*)walloc((size_t)N * 4);
  int*   col    = (int*)walloc((size_t)E * 4);
  int*   bsum   = (int*)walloc(256 * 4);
  int*   boff   = (int*)walloc(256 * 4);
  float* pooled = (float*)walloc(512 * 4);
  float* s_out  = (float*)walloc(512);
  int*   flag   = (int*)walloc(512);

  // graph structure (CSR by dst)
  detect_i64_kernel<<<1, 64, 0, stream>>>(ei, flag);
  init_kernel<<<(N + 255) / 256, 256, 0, stream>>>(cnt, fillc, pooled, N);
  count_kernel<<<(E + 255) / 256, 256, 0, stream>>>(ei, flag, cnt, E);
  bsum_kernel<<<B, 256, 0, stream>>>(cnt, bsum, N);
  bscan_kernel<<<1, 256, 0, stream>>>(bsum, boff, rowptr, B, N);
  rowptr_kernel<<<B, 256, 0, stream>>>(cnt, boff, rowptr, dinv, N);
  scatter_kernel<<<(E + 255) / 256, 256, 0, stream>>>(ei, flag, rowptr, fillc, col, E);

  // bf16 conversion + weight packing
  cvt_x_kernel<<<(Mpad * 64 + 255) / 256, 256, 0, stream>>>(x, xb, N * 64, Mpad * 64);
  pack_w_kernel<<<(2 * 16 * 64 + 255) / 256, 256, 0, stream>>>(W1, Wp1, 64);
  pack_w_kernel<<<(8 * 16 * 64 + 255) / 256, 256, 0, stream>>>(W2, Wp2, 256);
  for (int l = 0; l < 3; ++l)
    pack_w_kernel<<<(8 * 16 * 64 + 255) / 256, 256, 0, stream>>>(
        cW + (size_t)l * 256 * 256, Wpc + (size_t)l * 8 * 16 * 64 * 8, 256);

  int gblocks = Mpad / 64;
  // encoder
  gemm_mfma_kernel<<<gblocks, 256, 0, stream>>>(xb, Wp1, b1, nullptr, hA, N, 64, 1);
  gemm_mfma_kernel<<<gblocks, 256, 0, stream>>>(hA, Wp2, b2, nullptr, hB, N, 256, 0);
  // GCN layers: hw' = (h @ convW) * dinv[row]; h = relu(dinv*(gather+self) + b)
  for (int l = 0; l < 3; ++l) {
    gemm_mfma_kernel<<<gblocks, 256, 0, stream>>>(
        hB, Wpc + (size_t)l * 8 * 16 * 64 * 8, nullptr, dinv, hA, N, 256, 0);
    mp_kernel<<<N, 64, 0, stream>>>(hA, rowptr, col, dinv, cb + (size_t)l * 256, hB);
  }
  // readout
  pool_kernel<<<392, 256, 0, stream>>>(hB, pooled, (unsigned*)(pooled + 256), N);
  head_kernel<<<1, 256, 0, stream>>>(pooled, Wg1, bg1, Wg2, bg2, Wd1, bd1, Wd2, bd2, out, s_out, N);
  fill_kernel<<<(E + 255) / 256, 256, 0, stream>>>(out + 128, s_out, E);
}

// Round 5
// 489.233 us; speedup vs baseline: 2.2848x; 1.0397x over previous
//
#include <hip/hip_runtime.h>
#include <hip/hip_bf16.h>

// GAE forward, bf16 compute path + fp8 message tensor.
//   CSR build (count / 3-phase multiblock scan / scatter)
//   -> cvt x->bf16, pack weights to MFMA frag order
//   -> 5x bf16-MFMA GEMM (encoder x2 -> bf16 out; conv x3 -> fp8(x32)*dinv out)
//   -> 3x mp gather (fp8 rows, f32 accum, bf16 h out) -> grid-strided pool
//   -> head (f32) -> fill(sigmoid const)
// edge_probs is constant: node_emb rows are the same broadcast vector v,
// so logit = sum(v*v) for every edge.

typedef __attribute__((ext_vector_type(8))) short bf16x8;
typedef __attribute__((ext_vector_type(4))) float f32x4;
typedef __attribute__((ext_vector_type(2))) float f32x2;

#define FP8_SCALE 32.0f
#define FP8_INV (1.0f / 32.0f)

__device__ __forceinline__ ushort f2bf(float f) {
  union { float f; unsigned u; } v; v.f = f;
  unsigned r = v.u + 0x7FFF + ((v.u >> 16) & 1);  // RNE
  return (ushort)(r >> 16);
}
__device__ __forceinline__ float bf2f(ushort b) {
  union { unsigned u; float f; } v; v.u = ((unsigned)b) << 16;
  return v.f;
}

// -------------------- CSR build --------------------

__global__ void detect_i64_kernel(const int* __restrict__ ei, int* __restrict__ flag) {
  if (threadIdx.x == 0 && blockIdx.x == 0) {
    int all0 = 1;
    for (int i = 0; i < 128; ++i) {
      if (ei[2 * i + 1] != 0) { all0 = 0; break; }
    }
    flag[0] = all0;  // 1 => int64 payload (high words all zero)
  }
}

__global__ void init_kernel(int* __restrict__ cnt, int* __restrict__ fill,
                            float* __restrict__ pooled, int N) {
  int i = blockIdx.x * 256 + threadIdx.x;
  if (i < N) { cnt[i] = 0; fill[i] = 0; }
  if (i < 512) pooled[i] = 0.f;  // sum[0:256]=0, max bits[256:512]=+0.0 (h>=0)
}

__global__ void count_kernel(const int* __restrict__ ei, const int* __restrict__ flag,
                             int* __restrict__ cnt, int E) {
  int e = blockIdx.x * 256 + threadIdx.x;
  if (e >= E) return;
  int d;
  if (flag[0]) d = (int)((const long long*)ei)[(size_t)E + e];
  else         d = ei[(size_t)E + e];
  atomicAdd(&cnt[d], 1);
}

// 3-phase multiblock exclusive scan over cnt[N] -> rowptr[N+1], plus dinv.

__global__ __launch_bounds__(256) void bsum_kernel(const int* __restrict__ cnt,
                                                   int* __restrict__ bsum, int N) {
  __shared__ int red[4];
  int t = threadIdx.x;
  int i = blockIdx.x * 256 + t;
  int v = (i < N) ? cnt[i] : 0;
  for (int off = 32; off > 0; off >>= 1) v += __shfl_down(v, off, 64);
  if ((t & 63) == 0) red[t >> 6] = v;
  __syncthreads();
  if (t == 0) bsum[blockIdx.x] = red[0] + red[1] + red[2] + red[3];
}

__global__ __launch_bounds__(256) void bscan_kernel(const int* __restrict__ bsum,
                                                    int* __restrict__ boff,
                                                    int* __restrict__ rowptr, int B, int N) {
  __shared__ int s[256];
  int t = threadIdx.x;
  int v = (t < B) ? bsum[t] : 0;
  s[t] = v;
  __syncthreads();
  for (int off = 1; off < 256; off <<= 1) {
    int x = s[t];
    int add = (t >= off) ? s[t - off] : 0;
    __syncthreads();
    s[t] = x + add;
    __syncthreads();
  }
  if (t < B) boff[t] = s[t] - v;  // exclusive block offset
  if (t == 255) rowptr[N] = s[255];
}

__global__ __launch_bounds__(256) void rowptr_kernel(const int* __restrict__ cnt,
                                                     const int* __restrict__ boff,
                                                     int* __restrict__ rowptr,
                                                     float* __restrict__ dinv, int N) {
  __shared__ int s[256];
  int t = threadIdx.x;
  int i = blockIdx.x * 256 + t;
  int v = (i < N) ? cnt[i] : 0;
  s[t] = v;
  __syncthreads();
  for (int off = 1; off < 256; off <<= 1) {
    int x = s[t];
    int add = (t >= off) ? s[t - off] : 0;
    __syncthreads();
    s[t] = x + add;
    __syncthreads();
  }
  if (i < N) {
    rowptr[i] = boff[blockIdx.x] + s[t] - v;
    dinv[i] = rsqrtf((float)(v + 1));  // +1 self-loop
  }
}

__global__ void scatter_kernel(const int* __restrict__ ei, const int* __restrict__ flag,
                               const int* __restrict__ rowptr, int* __restrict__ fill,
                               int* __restrict__ col, int E) {
  int e = blockIdx.x * 256 + threadIdx.x;
  if (e >= E) return;
  int s, d;
  if (flag[0]) {
    const long long* e64 = (const long long*)ei;
    s = (int)e64[e];
    d = (int)e64[(size_t)E + e];
  } else {
    s = ei[e];
    d = ei[(size_t)E + e];
  }
  int pos = rowptr[d] + atomicAdd(&fill[d], 1);
  col[pos] = s;
}

// -------------------- bf16 conversion / weight packing --------------------

__global__ void cvt_x_kernel(const float* __restrict__ x, ushort* __restrict__ xb,
                             int n, int npad) {
  int i = blockIdx.x * 256 + threadIdx.x;
  if (i < n) xb[i] = f2bf(x[i]);
  else if (i < npad) xb[i] = 0;
}

// Wp layout: [K/32][16 colblk][64 lane][8 bf16], element (ks,cb,lane,i):
//   k = ks*32 + (lane>>4)*8 + i,  n = cb*16 + (lane&15)   (MFMA B-frag order)
__global__ void pack_w_kernel(const float* __restrict__ W, ushort* __restrict__ Wp, int K) {
  int idx = blockIdx.x * 256 + threadIdx.x;
  int total = (K >> 5) * 16 * 64;
  if (idx >= total) return;
  int lane = idx & 63;
  int cb = (idx >> 6) & 15;
  int ks = idx >> 10;
  int n = cb * 16 + (lane & 15);
  int kbase = ks * 32 + (lane >> 4) * 8;
#pragma unroll
  for (int i = 0; i < 8; ++i)
    Wp[(size_t)idx * 8 + i] = f2bf(W[(size_t)(kbase + i) * 256 + n]);
}

// -------------------- bf16 MFMA GEMM: C[M,256] = post(A[M,K] @ W) --------------------
// block = 256 thr (4 waves), tile 64 rows x 256 cols; wave w owns cols w*64..+63.
// Per wave: 4 rowblk x 4 colblk 16x16 frags, K-loop step 32.
// Output: bf16 to C, or (if C8) fp8 e4m3 of value*FP8_SCALE (post bias/relu/scale).

__global__ __launch_bounds__(256) void gemm_mfma_kernel(
    const ushort* __restrict__ A,   // [Mpad,K] bf16 row-major
    const ushort* __restrict__ Wp,  // packed frags
    const float* __restrict__ bias, // [256] or null
    const float* __restrict__ scale,// [M] dinv or null (applied after bias/relu)
    ushort* __restrict__ C,         // [Mpad,256] bf16 (if C8 == null)
    unsigned char* __restrict__ C8, // [Mpad,256] fp8 (or null)
    int M, int K, int relu) {
  int t = threadIdx.x;
  int lane = t & 63, wave = t >> 6;
  int l15 = lane & 15, lk = lane >> 4;
  int row0 = blockIdx.x * 64;

  f32x4 acc[4][4];
#pragma unroll
  for (int rb = 0; rb < 4; ++rb)
#pragma unroll
    for (int cb = 0; cb < 4; ++cb) acc[rb][cb] = (f32x4){0.f, 0.f, 0.f, 0.f};

  const ushort* abase[4];
#pragma unroll
  for (int rb = 0; rb < 4; ++rb)
    abase[rb] = A + (size_t)(row0 + rb * 16 + l15) * K + lk * 8;
  const ushort* bbase = Wp + ((size_t)(wave * 4) * 64 + lane) * 8;

  int nks = K >> 5;
  for (int ks = 0; ks < nks; ++ks) {
    bf16x8 a[4], b[4];
#pragma unroll
    for (int rb = 0; rb < 4; ++rb)
      a[rb] = *reinterpret_cast<const bf16x8*>(abase[rb] + ks * 32);
#pragma unroll
    for (int cb = 0; cb < 4; ++cb)
      b[cb] = *reinterpret_cast<const bf16x8*>(bbase + ((size_t)ks * 16 + cb) * 64 * 8);
#pragma unroll
    for (int rb = 0; rb < 4; ++rb)
#pragma unroll
      for (int cb = 0; cb < 4; ++cb)
        acc[rb][cb] = __builtin_amdgcn_mfma_f32_16x16x32_bf16(a[rb], b[cb], acc[rb][cb], 0, 0, 0);
  }

  float bv[4];
#pragma unroll
  for (int cb = 0; cb < 4; ++cb)
    bv[cb] = bias ? bias[wave * 64 + cb * 16 + l15] : 0.f;

#pragma unroll
  for (int rb = 0; rb < 4; ++rb) {
    int rbase = row0 + rb * 16 + lk * 4;
#pragma unroll
    for (int r = 0; r < 4; ++r) {
      int row = rbase + r;
      if (row >= M) continue;
      float sc = scale ? scale[row] : 1.f;
#pragma unroll
      for (int cb = 0; cb < 4; ++cb) {
        float v = acc[rb][cb][r] + bv[cb];
        if (relu) v = fmaxf(v, 0.f);
        v *= sc;
        int colIdx = wave * 64 + cb * 16 + l15;
        if (C8) {
          float vq = fminf(fmaxf(v * FP8_SCALE, -448.f), 448.f);
          unsigned p = __builtin_amdgcn_cvt_pk_fp8_f32(vq, vq, 0, false);
          C8[(size_t)row * 256 + colIdx] = (unsigned char)(p & 0xff);
        } else {
          C[(size_t)row * 256 + colIdx] = f2bf(v);
        }
      }
    }
  }
}

// -------- message passing: h[n] = relu(dinv[n]*(sum_{s in in(n)} hw'[s] + hw'[n]) + b) ----
// hw' rows are fp8 e4m3 of (hw * dinv[src] * FP8_SCALE); dn folds dinv[n]/FP8_SCALE.

__global__ __launch_bounds__(64) void mp_kernel(const unsigned char* __restrict__ hw8,
                                                const int* __restrict__ rowptr,
                                                const int* __restrict__ col,
                                                const float* __restrict__ dinv,
                                                const float* __restrict__ bias,
                                                ushort* __restrict__ hout) {
  int n = blockIdx.x;
  int t = threadIdx.x;  // 64 lanes x 4 fp8 = 256 cols
  const unsigned* hw32 = reinterpret_cast<const unsigned*>(hw8);
  unsigned ws = hw32[(size_t)n * 64 + t];  // self
  f32x2 lo = __builtin_amdgcn_cvt_pk_f32_fp8(ws, false);
  f32x2 hi = __builtin_amdgcn_cvt_pk_f32_fp8(ws, true);
  float ax = lo[0], ay = lo[1], az = hi[0], aw = hi[1];
  int beg = rowptr[n], end = rowptr[n + 1];
  for (int j = beg; j < end; ++j) {
    int s = col[j];
    unsigned wv = hw32[(size_t)s * 64 + t];
    f32x2 l2 = __builtin_amdgcn_cvt_pk_f32_fp8(wv, false);
    f32x2 h2 = __builtin_amdgcn_cvt_pk_f32_fp8(wv, true);
    ax += l2[0]; ay += l2[1]; az += h2[0]; aw += h2[1];
  }
  float dn = dinv[n] * FP8_INV;
  float4 bv = *reinterpret_cast<const float4*>(bias + t * 4);
  ushort4 o;
  o.x = f2bf(fmaxf(fmaf(dn, ax, bv.x), 0.f));
  o.y = f2bf(fmaxf(fmaf(dn, ay, bv.y), 0.f));
  o.z = f2bf(fmaxf(fmaf(dn, az, bv.z), 0.f));
  o.w = f2bf(fmaxf(fmaf(dn, aw, bv.w), 0.f));
  *reinterpret_cast<ushort4*>(hout + (size_t)n * 256 + t * 4) = o;
}

// ---------- pooling: column sum+max over N rows, grid-strided 2-level reduce ----------

__global__ __launch_bounds__(256) void pool_kernel(const ushort* __restrict__ h,
                                                   float* __restrict__ pooled_sum,
                                                   unsigned* __restrict__ pooled_max, int N) {
  __shared__ float ssum[4][256];
  __shared__ float smax[4][256];
  int t = threadIdx.x;
  int w = t >> 6, l = t & 63;
  int stride = gridDim.x * 4;
  float s0 = 0.f, s1 = 0.f, s2 = 0.f, s3 = 0.f;
  float m0 = 0.f, m1 = 0.f, m2 = 0.f, m3 = 0.f;  // h >= 0 after relu
  for (int r = blockIdx.x * 4 + w; r < N; r += stride) {
    ushort4 hv = *reinterpret_cast<const ushort4*>(h + (size_t)r * 256 + l * 4);
    float v0 = bf2f(hv.x), v1 = bf2f(hv.y), v2 = bf2f(hv.z), v3 = bf2f(hv.w);
    s0 += v0; s1 += v1; s2 += v2; s3 += v3;
    m0 = fmaxf(m0, v0); m1 = fmaxf(m1, v1); m2 = fmaxf(m2, v2); m3 = fmaxf(m3, v3);
  }
  ssum[w][l * 4] = s0; ssum[w][l * 4 + 1] = s1; ssum[w][l * 4 + 2] = s2; ssum[w][l * 4 + 3] = s3;
  smax[w][l * 4] = m0; smax[w][l * 4 + 1] = m1; smax[w][l * 4 + 2] = m2; smax[w][l * 4 + 3] = m3;
  __syncthreads();
  if (w == 0) {
#pragma unroll
    for (int j = 0; j < 4; ++j) {
      int c = l * 4 + j;
      float s = ssum[0][c] + ssum[1][c] + ssum[2][c] + ssum[3][c];
      float m = fmaxf(fmaxf(smax[0][c], smax[1][c]), fmaxf(smax[2][c], smax[3][c]));
      atomicAdd(&pooled_sum[c], s);
      atomicMax(&pooled_max[c], __float_as_uint(m));  // valid: non-negative floats
    }
  }
}

// -------------------- head: graph projection + decoder + scalar logit (f32) ------------

__global__ __launch_bounds__(256) void head_kernel(const float* __restrict__ pooled,
                                                   const float* __restrict__ Wg1, const float* __restrict__ bg1,
                                                   const float* __restrict__ Wg2, const float* __restrict__ bg2,
                                                   const float* __restrict__ Wd1, const float* __restrict__ bd1,
                                                   const float* __restrict__ Wd2, const float* __restrict__ bd2,
                                                   float* __restrict__ out_ge, float* __restrict__ s_out, int N) {
  __shared__ float gr[512];
  __shared__ float t1[256];
  __shared__ float ge[128];
  __shared__ float t2[256];
  __shared__ float v[256];
  __shared__ float red[4];
  int t = threadIdx.x;
  gr[t] = pooled[t] / (float)N;                                       // mean
  gr[256 + t] = __uint_as_float(((const unsigned*)pooled)[256 + t]);  // max (bit-stored)
  __syncthreads();
  float acc = bg1[t];
  for (int k = 0; k < 512; ++k) acc = fmaf(gr[k], Wg1[k * 256 + t], acc);
  t1[t] = fmaxf(acc, 0.f);
  __syncthreads();
  if (t < 128) {
    float a = bg2[t];
    for (int k = 0; k < 256; ++k) a = fmaf(t1[k], Wg2[k * 128 + t], a);
    ge[t] = a;
    out_ge[t] = a;  // output 0: graph_embedding
  }
  __syncthreads();
  acc = bd1[t];
  for (int k = 0; k < 128; ++k) acc = fmaf(ge[k], Wd1[k * 256 + t], acc);
  t2[t] = fmaxf(acc, 0.f);
  __syncthreads();
  acc = bd2[t];
  for (int k = 0; k < 256; ++k) acc = fmaf(t2[k], Wd2[k * 256 + t], acc);
  v[t] = acc;
  __syncthreads();
  float p = v[t] * v[t];
  for (int off = 32; off > 0; off >>= 1) p += __shfl_down(p, off, 64);
  if ((t & 63) == 0) red[t >> 6] = p;
  __syncthreads();
  if (t == 0) {
    float ssq = red[0] + red[1] + red[2] + red[3];
    s_out[0] = 1.f / (1.f + expf(-ssq));
  }
}

__global__ void fill_kernel(float* __restrict__ out, const float* __restrict__ s_out, int E) {
  int i = blockIdx.x * 256 + threadIdx.x;
  if (i < E) out[i] = s_out[0];
}

// -------------------- launch --------------------

extern "C" void kernel_launch(void* const* d_in, const int* in_sizes, int n_in,
                              void* d_out, int out_size, void* d_ws, size_t ws_size,
                              hipStream_t stream) {
  const float* x   = (const float*)d_in[0];
  const int*   ei  = (const int*)d_in[1];
  const float* W1  = (const float*)d_in[2];
  const float* b1  = (const float*)d_in[3];
  const float* W2  = (const float*)d_in[4];
  const float* b2  = (const float*)d_in[5];
  const float* cW  = (const float*)d_in[6];
  const float* cb  = (const float*)d_in[7];
  const float* Wg1 = (const float*)d_in[8];
  const float* bg1 = (const float*)d_in[9];
  const float* Wg2 = (const float*)d_in[10];
  const float* bg2 = (const float*)d_in[11];
  const float* Wd1 = (const float*)d_in[12];
  const float* bd1 = (const float*)d_in[13];
  const float* Wd2 = (const float*)d_in[14];
  const float* bd2 = (const float*)d_in[15];
  float* out = (float*)d_out;

  int N = in_sizes[0] / 64;  // 50000
  int E = in_sizes[1] / 2;   // 800000
  int Mpad = (N + 63) & ~63; // 50048
  int B = (N + 255) / 256;   // scan blocks (196)

  size_t off = 0;
  auto walloc = [&](size_t bytes) -> void* {
    void* p = (char*)d_ws + off;
    off += (bytes + 511) & ~(size_t)511;
    return p;
  };
  ushort* hA    = (ushort*)walloc((size_t)Mpad * 256 * 2);
  ushort* hB    = (ushort*)walloc((size_t)Mpad * 256 * 2);
  unsigned char* hA8 = (unsigned char*)walloc((size_t)Mpad * 256);
  ushort* xb    = (ushort*)walloc((size_t)Mpad * 64 * 2);
  ushort* Wp1   = (ushort*)walloc((size_t)2 * 16 * 64 * 8 * 2);
  ushort* Wp2   = (ushort*)walloc((size_t)8 * 16 * 64 * 8 * 2);
  ushort* Wpc   = (ushort*)walloc((size_t)3 * 8 * 16 * 64 * 8 * 2);
  int*   cnt    = (int*)walloc((size_t)N * 4);
  int*   fillc  = (int*)walloc((size_t)N * 4);
  int*   rowptr = (int*)walloc(((size_t)N + 1) * 4);
  float* dinv   = (float*)walloc((size_t)N * 4);
  int*   col    = (int*)walloc((size_t)E * 4);
  int*   bsum   = (int*)walloc(256 * 4);
  int*   boff   = (int*)walloc(256 * 4);
  float* pooled = (float*)walloc(512 * 4);
  float* s_out  = (float*)walloc(512);
  int*   flag   = (int*)walloc(512);

  // graph structure (CSR by dst)
  detect_i64_kernel<<<1, 64, 0, stream>>>(ei, flag);
  init_kernel<<<(N + 255) / 256, 256, 0, stream>>>(cnt, fillc, pooled, N);
  count_kernel<<<(E + 255) / 256, 256, 0, stream>>>(ei, flag, cnt, E);
  bsum_kernel<<<B, 256, 0, stream>>>(cnt, bsum, N);
  bscan_kernel<<<1, 256, 0, stream>>>(bsum, boff, rowptr, B, N);
  rowptr_kernel<<<B, 256, 0, stream>>>(cnt, boff, rowptr, dinv, N);
  scatter_kernel<<<(E + 255) / 256, 256, 0, stream>>>(ei, flag, rowptr, fillc, col, E);

  // bf16 conversion + weight packing
  cvt_x_kernel<<<(Mpad * 64 + 255) / 256, 256, 0, stream>>>(x, xb, N * 64, Mpad * 64);
  pack_w_kernel<<<(2 * 16 * 64 + 255) / 256, 256, 0, stream>>>(W1, Wp1, 64);
  pack_w_kernel<<<(8 * 16 * 64 + 255) / 256, 256, 0, stream>>>(W2, Wp2, 256);
  for (int l = 0; l < 3; ++l)
    pack_w_kernel<<<(8 * 16 * 64 + 255) / 256, 256, 0, stream>>>(
        cW + (size_t)l * 256 * 256, Wpc + (size_t)l * 8 * 16 * 64 * 8, 256);

  int gblocks = Mpad / 64;
  // encoder (bf16 out)
  gemm_mfma_kernel<<<gblocks, 256, 0, stream>>>(xb, Wp1, b1, nullptr, hA, nullptr, N, 64, 1);
  gemm_mfma_kernel<<<gblocks, 256, 0, stream>>>(hA, Wp2, b2, nullptr, hB, nullptr, N, 256, 0);
  // GCN layers: hw' = (h @ convW) * dinv[row] -> fp8(x32); h = relu(dinv*(gather+self) + b)
  for (int l = 0; l < 3; ++l) {
    gemm_mfma_kernel<<<gblocks, 256, 0, stream>>>(
        hB, Wpc + (size_t)l * 8 * 16 * 64 * 8, nullptr, dinv, nullptr, hA8, N, 256, 0);
    mp_kernel<<<N, 64, 0, stream>>>(hA8, rowptr, col, dinv, cb + (size_t)l * 256, hB);
  }
  // readout
  pool_kernel<<<392, 256, 0, stream>>>(hB, pooled, (unsigned*)(pooled + 256), N);
  head_kernel<<<1, 256, 0, stream>>>(pooled, Wg1, bg1, Wg2, bg2, Wd1, bd1, Wd2, bd2, out, s_out, N);
  fill_kernel<<<(E + 255) / 256, 256, 0, stream>>>(out + 128, s_out, E);
}

// Round 6
// 439.468 us; speedup vs baseline: 2.5435x; 1.1132x over previous
//
#include <hip/hip_runtime.h>
#include <hip/hip_bf16.h>

// GAE forward, bf16 compute path + fp8 message tensor.
//   CSR build (count / 3-phase multiblock scan / cursor-scatter)
//   -> cvt x->bf16, pack weights to MFMA frag order
//   -> 5x bf16-MFMA GEMM (encoder x2 -> bf16 out; conv x3 -> fp8(x32)*dinv out)
//   -> 3x mp gather (fp8 rows, x4-unrolled, f32 accum, bf16 h out)
//   -> grid-strided pool -> head (f32) -> fill(sigmoid const)
// edge_probs is constant: node_emb rows are the same broadcast vector v,
// so logit = sum(v*v) for every edge.

typedef __attribute__((ext_vector_type(8))) short bf16x8;
typedef __attribute__((ext_vector_type(4))) float f32x4;
typedef __attribute__((ext_vector_type(2))) float f32x2;

#define FP8_SCALE 32.0f
#define FP8_INV (1.0f / 32.0f)

__device__ __forceinline__ ushort f2bf(float f) {
  union { float f; unsigned u; } v; v.f = f;
  unsigned r = v.u + 0x7FFF + ((v.u >> 16) & 1);  // RNE
  return (ushort)(r >> 16);
}
__device__ __forceinline__ float bf2f(ushort b) {
  union { unsigned u; float f; } v; v.u = ((unsigned)b) << 16;
  return v.f;
}

// -------------------- CSR build --------------------

__global__ void detect_i64_kernel(const int* __restrict__ ei, int* __restrict__ flag) {
  if (threadIdx.x == 0 && blockIdx.x == 0) {
    int all0 = 1;
    for (int i = 0; i < 128; ++i) {
      if (ei[2 * i + 1] != 0) { all0 = 0; break; }
    }
    flag[0] = all0;  // 1 => int64 payload (high words all zero)
  }
}

__global__ void init_kernel(int* __restrict__ cnt, float* __restrict__ pooled, int N) {
  int i = blockIdx.x * 256 + threadIdx.x;
  if (i < N) cnt[i] = 0;
  if (i < 512) pooled[i] = 0.f;  // sum[0:256]=0, max bits[256:512]=+0.0 (h>=0)
}

__global__ void count_kernel(const int* __restrict__ ei, const int* __restrict__ flag,
                             int* __restrict__ cnt, int E) {
  int e = blockIdx.x * 256 + threadIdx.x;
  if (e >= E) return;
  int d;
  if (flag[0]) d = (int)((const long long*)ei)[(size_t)E + e];
  else         d = ei[(size_t)E + e];
  atomicAdd(&cnt[d], 1);
}

// 3-phase multiblock exclusive scan over cnt[N] -> rowptr[N+1] (+cursor copy), plus dinv.

__global__ __launch_bounds__(256) void bsum_kernel(const int* __restrict__ cnt,
                                                   int* __restrict__ bsum, int N) {
  __shared__ int red[4];
  int t = threadIdx.x;
  int i = blockIdx.x * 256 + t;
  int v = (i < N) ? cnt[i] : 0;
  for (int off = 32; off > 0; off >>= 1) v += __shfl_down(v, off, 64);
  if ((t & 63) == 0) red[t >> 6] = v;
  __syncthreads();
  if (t == 0) bsum[blockIdx.x] = red[0] + red[1] + red[2] + red[3];
}

__global__ __launch_bounds__(256) void bscan_kernel(const int* __restrict__ bsum,
                                                    int* __restrict__ boff,
                                                    int* __restrict__ rowptr, int B, int N) {
  __shared__ int s[256];
  int t = threadIdx.x;
  int v = (t < B) ? bsum[t] : 0;
  s[t] = v;
  __syncthreads();
  for (int off = 1; off < 256; off <<= 1) {
    int x = s[t];
    int add = (t >= off) ? s[t - off] : 0;
    __syncthreads();
    s[t] = x + add;
    __syncthreads();
  }
  if (t < B) boff[t] = s[t] - v;  // exclusive block offset
  if (t == 255) rowptr[N] = s[255];
}

__global__ __launch_bounds__(256) void rowptr_kernel(const int* __restrict__ cnt,
                                                     const int* __restrict__ boff,
                                                     int* __restrict__ rowptr,
                                                     int* __restrict__ cursor,
                                                     float* __restrict__ dinv, int N) {
  __shared__ int s[256];
  int t = threadIdx.x;
  int i = blockIdx.x * 256 + t;
  int v = (i < N) ? cnt[i] : 0;
  s[t] = v;
  __syncthreads();
  for (int off = 1; off < 256; off <<= 1) {
    int x = s[t];
    int add = (t >= off) ? s[t - off] : 0;
    __syncthreads();
    s[t] = x + add;
    __syncthreads();
  }
  if (i < N) {
    int rp = boff[blockIdx.x] + s[t] - v;
    rowptr[i] = rp;
    cursor[i] = rp;  // running cursor for scatter
    dinv[i] = rsqrtf((float)(v + 1));  // +1 self-loop
  }
}

// cursor-based counting-sort scatter: one atomic per edge, returns slot directly.
__global__ void scatter_kernel(const int* __restrict__ ei, const int* __restrict__ flag,
                               int* __restrict__ cursor, int* __restrict__ col, int E) {
  int e = blockIdx.x * 256 + threadIdx.x;
  if (e >= E) return;
  int s, d;
  if (flag[0]) {
    const long long* e64 = (const long long*)ei;
    s = (int)e64[e];
    d = (int)e64[(size_t)E + e];
  } else {
    s = ei[e];
    d = ei[(size_t)E + e];
  }
  int pos = atomicAdd(&cursor[d], 1);
  col[pos] = s;
}

// -------------------- bf16 conversion / weight packing --------------------

__global__ void cvt_x_kernel(const float* __restrict__ x, ushort* __restrict__ xb,
                             int n, int npad) {
  int i = blockIdx.x * 256 + threadIdx.x;
  if (i < n) xb[i] = f2bf(x[i]);
  else if (i < npad) xb[i] = 0;
}

// Wp layout: [K/32][16 colblk][64 lane][8 bf16], element (ks,cb,lane,i):
//   k = ks*32 + (lane>>4)*8 + i,  n = cb*16 + (lane&15)   (MFMA B-frag order)
__global__ void pack_w_kernel(const float* __restrict__ W, ushort* __restrict__ Wp, int K) {
  int idx = blockIdx.x * 256 + threadIdx.x;
  int total = (K >> 5) * 16 * 64;
  if (idx >= total) return;
  int lane = idx & 63;
  int cb = (idx >> 6) & 15;
  int ks = idx >> 10;
  int n = cb * 16 + (lane & 15);
  int kbase = ks * 32 + (lane >> 4) * 8;
#pragma unroll
  for (int i = 0; i < 8; ++i)
    Wp[(size_t)idx * 8 + i] = f2bf(W[(size_t)(kbase + i) * 256 + n]);
}

// -------------------- bf16 MFMA GEMM: C[M,256] = post(A[M,K] @ W) --------------------
// block = 256 thr (4 waves), tile 64 rows x 256 cols; wave w owns cols w*64..+63.
// Per wave: 4 rowblk x 4 colblk 16x16 frags, K-loop step 32.
// Output: bf16 to C, or (if C8) fp8 e4m3 of value*FP8_SCALE (post bias/relu/scale).

__global__ __launch_bounds__(256) void gemm_mfma_kernel(
    const ushort* __restrict__ A,   // [Mpad,K] bf16 row-major
    const ushort* __restrict__ Wp,  // packed frags
    const float* __restrict__ bias, // [256] or null
    const float* __restrict__ scale,// [M] dinv or null (applied after bias/relu)
    ushort* __restrict__ C,         // [Mpad,256] bf16 (if C8 == null)
    unsigned char* __restrict__ C8, // [Mpad,256] fp8 (or null)
    int M, int K, int relu) {
  int t = threadIdx.x;
  int lane = t & 63, wave = t >> 6;
  int l15 = lane & 15, lk = lane >> 4;
  int row0 = blockIdx.x * 64;

  f32x4 acc[4][4];
#pragma unroll
  for (int rb = 0; rb < 4; ++rb)
#pragma unroll
    for (int cb = 0; cb < 4; ++cb) acc[rb][cb] = (f32x4){0.f, 0.f, 0.f, 0.f};

  const ushort* abase[4];
#pragma unroll
  for (int rb = 0; rb < 4; ++rb)
    abase[rb] = A + (size_t)(row0 + rb * 16 + l15) * K + lk * 8;
  const ushort* bbase = Wp + ((size_t)(wave * 4) * 64 + lane) * 8;

  int nks = K >> 5;
  for (int ks = 0; ks < nks; ++ks) {
    bf16x8 a[4], b[4];
#pragma unroll
    for (int rb = 0; rb < 4; ++rb)
      a[rb] = *reinterpret_cast<const bf16x8*>(abase[rb] + ks * 32);
#pragma unroll
    for (int cb = 0; cb < 4; ++cb)
      b[cb] = *reinterpret_cast<const bf16x8*>(bbase + ((size_t)ks * 16 + cb) * 64 * 8);
#pragma unroll
    for (int rb = 0; rb < 4; ++rb)
#pragma unroll
      for (int cb = 0; cb < 4; ++cb)
        acc[rb][cb] = __builtin_amdgcn_mfma_f32_16x16x32_bf16(a[rb], b[cb], acc[rb][cb], 0, 0, 0);
  }

  float bv[4];
#pragma unroll
  for (int cb = 0; cb < 4; ++cb)
    bv[cb] = bias ? bias[wave * 64 + cb * 16 + l15] : 0.f;

#pragma unroll
  for (int rb = 0; rb < 4; ++rb) {
    int rbase = row0 + rb * 16 + lk * 4;
#pragma unroll
    for (int r = 0; r < 4; ++r) {
      int row = rbase + r;
      if (row >= M) continue;
      float sc = scale ? scale[row] : 1.f;
#pragma unroll
      for (int cb = 0; cb < 4; ++cb) {
        float v = acc[rb][cb][r] + bv[cb];
        if (relu) v = fmaxf(v, 0.f);
        v *= sc;
        int colIdx = wave * 64 + cb * 16 + l15;
        if (C8) {
          float vq = fminf(fmaxf(v * FP8_SCALE, -448.f), 448.f);
          unsigned p = __builtin_amdgcn_cvt_pk_fp8_f32(vq, vq, 0, false);
          C8[(size_t)row * 256 + colIdx] = (unsigned char)(p & 0xff);
        } else {
          C[(size_t)row * 256 + colIdx] = f2bf(v);
        }
      }
    }
  }
}

// -------- message passing: h[n] = relu(dinv[n]*(sum_{s in in(n)} hw'[s] + hw'[n]) + b) ----
// hw' rows are fp8 e4m3 of (hw * dinv[src] * FP8_SCALE); dn folds dinv[n]/FP8_SCALE.
// Edge loop unrolled x4 with independent loads to raise memory-level parallelism.

__global__ __launch_bounds__(64) void mp_kernel(const unsigned char* __restrict__ hw8,
                                                const int* __restrict__ rowptr,
                                                const int* __restrict__ col,
                                                const float* __restrict__ dinv,
                                                const float* __restrict__ bias,
                                                ushort* __restrict__ hout) {
  int n = blockIdx.x;
  int t = threadIdx.x;  // 64 lanes x 4 fp8 = 256 cols
  const unsigned* hw32 = reinterpret_cast<const unsigned*>(hw8);
  unsigned ws = hw32[(size_t)n * 64 + t];  // self
  f32x2 lo = __builtin_amdgcn_cvt_pk_f32_fp8(ws, false);
  f32x2 hi = __builtin_amdgcn_cvt_pk_f32_fp8(ws, true);
  float ax = lo[0], ay = lo[1], az = hi[0], aw = hi[1];
  int beg = rowptr[n], end = rowptr[n + 1];
  int j = beg;
  for (; j + 4 <= end; j += 4) {
    int s0 = col[j], s1 = col[j + 1], s2 = col[j + 2], s3 = col[j + 3];
    unsigned w0 = hw32[(size_t)s0 * 64 + t];
    unsigned w1 = hw32[(size_t)s1 * 64 + t];
    unsigned w2 = hw32[(size_t)s2 * 64 + t];
    unsigned w3 = hw32[(size_t)s3 * 64 + t];
    f32x2 l0 = __builtin_amdgcn_cvt_pk_f32_fp8(w0, false);
    f32x2 h0 = __builtin_amdgcn_cvt_pk_f32_fp8(w0, true);
    f32x2 l1 = __builtin_amdgcn_cvt_pk_f32_fp8(w1, false);
    f32x2 h1 = __builtin_amdgcn_cvt_pk_f32_fp8(w1, true);
    f32x2 l2 = __builtin_amdgcn_cvt_pk_f32_fp8(w2, false);
    f32x2 h2 = __builtin_amdgcn_cvt_pk_f32_fp8(w2, true);
    f32x2 l3 = __builtin_amdgcn_cvt_pk_f32_fp8(w3, false);
    f32x2 h3 = __builtin_amdgcn_cvt_pk_f32_fp8(w3, true);
    ax += (l0[0] + l1[0]) + (l2[0] + l3[0]);
    ay += (l0[1] + l1[1]) + (l2[1] + l3[1]);
    az += (h0[0] + h1[0]) + (h2[0] + h3[0]);
    aw += (h0[1] + h1[1]) + (h2[1] + h3[1]);
  }
  for (; j < end; ++j) {
    int s = col[j];
    unsigned wv = hw32[(size_t)s * 64 + t];
    f32x2 l2 = __builtin_amdgcn_cvt_pk_f32_fp8(wv, false);
    f32x2 h2 = __builtin_amdgcn_cvt_pk_f32_fp8(wv, true);
    ax += l2[0]; ay += l2[1]; az += h2[0]; aw += h2[1];
  }
  float dn = dinv[n] * FP8_INV;
  float4 bv = *reinterpret_cast<const float4*>(bias + t * 4);
  ushort4 o;
  o.x = f2bf(fmaxf(fmaf(dn, ax, bv.x), 0.f));
  o.y = f2bf(fmaxf(fmaf(dn, ay, bv.y), 0.f));
  o.z = f2bf(fmaxf(fmaf(dn, az, bv.z), 0.f));
  o.w = f2bf(fmaxf(fmaf(dn, aw, bv.w), 0.f));
  *reinterpret_cast<ushort4*>(hout + (size_t)n * 256 + t * 4) = o;
}

// ---------- pooling: column sum+max over N rows, grid-strided 2-level reduce ----------

__global__ __launch_bounds__(256) void pool_kernel(const ushort* __restrict__ h,
                                                   float* __restrict__ pooled_sum,
                                                   unsigned* __restrict__ pooled_max, int N) {
  __shared__ float ssum[4][256];
  __shared__ float smax[4][256];
  int t = threadIdx.x;
  int w = t >> 6, l = t & 63;
  int stride = gridDim.x * 4;
  float s0 = 0.f, s1 = 0.f, s2 = 0.f, s3 = 0.f;
  float m0 = 0.f, m1 = 0.f, m2 = 0.f, m3 = 0.f;  // h >= 0 after relu
  for (int r = blockIdx.x * 4 + w; r < N; r += stride) {
    ushort4 hv = *reinterpret_cast<const ushort4*>(h + (size_t)r * 256 + l * 4);
    float v0 = bf2f(hv.x), v1 = bf2f(hv.y), v2 = bf2f(hv.z), v3 = bf2f(hv.w);
    s0 += v0; s1 += v1; s2 += v2; s3 += v3;
    m0 = fmaxf(m0, v0); m1 = fmaxf(m1, v1); m2 = fmaxf(m2, v2); m3 = fmaxf(m3, v3);
  }
  ssum[w][l * 4] = s0; ssum[w][l * 4 + 1] = s1; ssum[w][l * 4 + 2] = s2; ssum[w][l * 4 + 3] = s3;
  smax[w][l * 4] = m0; smax[w][l * 4 + 1] = m1; smax[w][l * 4 + 2] = m2; smax[w][l * 4 + 3] = m3;
  __syncthreads();
  if (w == 0) {
#pragma unroll
    for (int j = 0; j < 4; ++j) {
      int c = l * 4 + j;
      float s = ssum[0][c] + ssum[1][c] + ssum[2][c] + ssum[3][c];
      float m = fmaxf(fmaxf(smax[0][c], smax[1][c]), fmaxf(smax[2][c], smax[3][c]));
      atomicAdd(&pooled_sum[c], s);
      atomicMax(&pooled_max[c], __float_as_uint(m));  // valid: non-negative floats
    }
  }
}

// -------------------- head: graph projection + decoder + scalar logit (f32) ------------

__global__ __launch_bounds__(256) void head_kernel(const float* __restrict__ pooled,
                                                   const float* __restrict__ Wg1, const float* __restrict__ bg1,
                                                   const float* __restrict__ Wg2, const float* __restrict__ bg2,
                                                   const float* __restrict__ Wd1, const float* __restrict__ bd1,
                                                   const float* __restrict__ Wd2, const float* __restrict__ bd2,
                                                   float* __restrict__ out_ge, float* __restrict__ s_out, int N) {
  __shared__ float gr[512];
  __shared__ float t1[256];
  __shared__ float ge[128];
  __shared__ float t2[256];
  __shared__ float v[256];
  __shared__ float red[4];
  int t = threadIdx.x;
  gr[t] = pooled[t] / (float)N;                                       // mean
  gr[256 + t] = __uint_as_float(((const unsigned*)pooled)[256 + t]);  // max (bit-stored)
  __syncthreads();
  float acc = bg1[t];
  for (int k = 0; k < 512; ++k) acc = fmaf(gr[k], Wg1[k * 256 + t], acc);
  t1[t] = fmaxf(acc, 0.f);
  __syncthreads();
  if (t < 128) {
    float a = bg2[t];
    for (int k = 0; k < 256; ++k) a = fmaf(t1[k], Wg2[k * 128 + t], a);
    ge[t] = a;
    out_ge[t] = a;  // output 0: graph_embedding
  }
  __syncthreads();
  acc = bd1[t];
  for (int k = 0; k < 128; ++k) acc = fmaf(ge[k], Wd1[k * 256 + t], acc);
  t2[t] = fmaxf(acc, 0.f);
  __syncthreads();
  acc = bd2[t];
  for (int k = 0; k < 256; ++k) acc = fmaf(t2[k], Wd2[k * 256 + t], acc);
  v[t] = acc;
  __syncthreads();
  float p = v[t] * v[t];
  for (int off = 32; off > 0; off >>= 1) p += __shfl_down(p, off, 64);
  if ((t & 63) == 0) red[t >> 6] = p;
  __syncthreads();
  if (t == 0) {
    float ssq = red[0] + red[1] + red[2] + red[3];
    s_out[0] = 1.f / (1.f + expf(-ssq));
  }
}

__global__ void fill_kernel(float* __restrict__ out, const float* __restrict__ s_out, int E) {
  int i = blockIdx.x * 256 + threadIdx.x;
  if (i < E) out[i] = s_out[0];
}

// -------------------- launch --------------------

extern "C" void kernel_launch(void* const* d_in, const int* in_sizes, int n_in,
                              void* d_out, int out_size, void* d_ws, size_t ws_size,
                              hipStream_t stream) {
  const float* x   = (const float*)d_in[0];
  const int*   ei  = (const int*)d_in[1];
  const float* W1  = (const float*)d_in[2];
  const float* b1  = (const float*)d_in[3];
  const float* W2  = (const float*)d_in[4];
  const float* b2  = (const float*)d_in[5];
  const float* cW  = (const float*)d_in[6];
  const float* cb  = (const float*)d_in[7];
  const float* Wg1 = (const float*)d_in[8];
  const float* bg1 = (const float*)d_in[9];
  const float* Wg2 = (const float*)d_in[10];
  const float* bg2 = (const float*)d_in[11];
  const float* Wd1 = (const float*)d_in[12];
  const float* bd1 = (const float*)d_in[13];
  const float* Wd2 = (const float*)d_in[14];
  const float* bd2 = (const float*)d_in[15];
  float* out = (float*)d_out;

  int N = in_sizes[0] / 64;  // 50000
  int E = in_sizes[1] / 2;   // 800000
  int Mpad = (N + 63) & ~63; // 50048
  int B = (N + 255) / 256;   // scan blocks (196)

  size_t off = 0;
  auto walloc = [&](size_t bytes) -> void* {
    void* p = (char*)d_ws + off;
    off += (bytes + 511) & ~(size_t)511;
    return p;
  };
  ushort* hA    = (ushort*)walloc((size_t)Mpad * 256 * 2);
  ushort* hB    = (ushort*)walloc((size_t)Mpad * 256 * 2);
  unsigned char* hA8 = (unsigned char*)walloc((size_t)Mpad * 256);
  ushort* xb    = (ushort*)walloc((size_t)Mpad * 64 * 2);
  ushort* Wp1   = (ushort*)walloc((size_t)2 * 16 * 64 * 8 * 2);
  ushort* Wp2   = (ushort*)walloc((size_t)8 * 16 * 64 * 8 * 2);
  ushort* Wpc   = (ushort*)walloc((size_t)3 * 8 * 16 * 64 * 8 * 2);
  int*   cnt    = (int*)walloc((size_t)N * 4);
  int*   rowptr = (int*)walloc(((size_t)N + 1) * 4);
  int*   cursor = (int*)walloc((size_t)N * 4);
  float* dinv   = (float*)walloc((size_t)N * 4);
  int*   col    = (int*)walloc((size_t)E * 4);
  int*   bsum   = (int*)walloc(256 * 4);
  int*   boff   = (int*)walloc(256 * 4);
  float* pooled = (float*)walloc(512 * 4);
  float* s_out  = (float*)walloc(512);
  int*   flag   = (int*)walloc(512);

  // graph structure (CSR by dst)
  detect_i64_kernel<<<1, 64, 0, stream>>>(ei, flag);
  init_kernel<<<(N + 255) / 256, 256, 0, stream>>>(cnt, pooled, N);
  count_kernel<<<(E + 255) / 256, 256, 0, stream>>>(ei, flag, cnt, E);
  bsum_kernel<<<B, 256, 0, stream>>>(cnt, bsum, N);
  bscan_kernel<<<1, 256, 0, stream>>>(bsum, boff, rowptr, B, N);
  rowptr_kernel<<<B, 256, 0, stream>>>(cnt, boff, rowptr, cursor, dinv, N);
  scatter_kernel<<<(E + 255) / 256, 256, 0, stream>>>(ei, flag, cursor, col, E);

  // bf16 conversion + weight packing
  cvt_x_kernel<<<(Mpad * 64 + 255) / 256, 256, 0, stream>>>(x, xb, N * 64, Mpad * 64);
  pack_w_kernel<<<(2 * 16 * 64 + 255) / 256, 256, 0, stream>>>(W1, Wp1, 64);
  pack_w_kernel<<<(8 * 16 * 64 + 255) / 256, 256, 0, stream>>>(W2, Wp2, 256);
  for (int l = 0; l < 3; ++l)
    pack_w_kernel<<<(8 * 16 * 64 + 255) / 256, 256, 0, stream>>>(
        cW + (size_t)l * 256 * 256, Wpc + (size_t)l * 8 * 16 * 64 * 8, 256);

  int gblocks = Mpad / 64;
  // encoder (bf16 out)
  gemm_mfma_kernel<<<gblocks, 256, 0, stream>>>(xb, Wp1, b1, nullptr, hA, nullptr, N, 64, 1);
  gemm_mfma_kernel<<<gblocks, 256, 0, stream>>>(hA, Wp2, b2, nullptr, hB, nullptr, N, 256, 0);
  // GCN layers: hw' = (h @ convW) * dinv[row] -> fp8(x32); h = relu(dinv*(gather+self) + b)
  for (int l = 0; l < 3; ++l) {
    gemm_mfma_kernel<<<gblocks, 256, 0, stream>>>(
        hB, Wpc + (size_t)l * 8 * 16 * 64 * 8, nullptr, dinv, nullptr, hA8, N, 256, 0);
    mp_kernel<<<N, 64, 0, stream>>>(hA8, rowptr, col, dinv, cb + (size_t)l * 256, hB);
  }
  // readout
  pool_kernel<<<392, 256, 0, stream>>>(hB, pooled, (unsigned*)(pooled + 256), N);
  head_kernel<<<1, 256, 0, stream>>>(pooled, Wg1, bg1, Wg2, bg2, Wd1, bd1, Wd2, bd2, out, s_out, N);
  fill_kernel<<<(E + 255) / 256, 256, 0, stream>>>(out + 128, s_out, E);
}